// Round 7
// baseline (1325.316 us; speedup 1.0000x reference)
//
#include <hip/hip_runtime.h>
#include <math.h>

#define B_ 32
#define S_ 256
#define E_ 768
#define H_ 12
#define L_ 2
#define FF_ 2048
#define NEGV -1e30f

typedef __attribute__((ext_vector_type(8))) short bf16x8;
typedef __attribute__((ext_vector_type(4))) float f32x4;

// ---------- bf16 split helpers ----------
__device__ __forceinline__ short bf16_rne(float x) {
  unsigned u = __float_as_uint(x);
  u += 0x7fffu + ((u >> 16) & 1u);
  return (short)(u >> 16);
}
__device__ __forceinline__ float bf16_to_f32(short h) {
  return __uint_as_float(((unsigned)(unsigned short)h) << 16);
}
__device__ __forceinline__ void split_bf16(float v, short& h, short& l) {
  h = bf16_rne(v);
  l = bf16_rne(v - bf16_to_f32(h));
}

__device__ __forceinline__ void gl2lds16(const short* g, short* s) {
  __builtin_amdgcn_global_load_lds((const __attribute__((address_space(1))) void*)g,
                                   (__attribute__((address_space(3))) void*)s, 16, 0, 0);
}

// ---------------- block-wide sum over 256 threads ----------------
__device__ __forceinline__ float block_sum256(float v) {
  __shared__ float sh[4];
  int lane = threadIdx.x & 63, w = threadIdx.x >> 6;
#pragma unroll
  for (int off = 32; off; off >>= 1) v += __shfl_down(v, off);
  if (lane == 0) sh[w] = v;
  __syncthreads();
  float tot = sh[0] + sh[1] + sh[2] + sh[3];
  __syncthreads();
  return tot;
}

// ---------------- embed + LN (emits f32 + bf16 split planes) ----------------
__global__ __launch_bounds__(256) void embed_ln_kernel(
    const float* __restrict__ tok, const int* __restrict__ pos,
    const int* __restrict__ typ, const float* __restrict__ pe,
    const float* __restrict__ temb, const float* __restrict__ w,
    const float* __restrict__ b, float* __restrict__ out,
    short* __restrict__ ohi, short* __restrict__ olo) {
  int row = blockIdx.x;
  int t = threadIdx.x;
  int p = pos[row], ty = typ[row];
  const float* tr = tok + (size_t)row * E_;
  const float* pr = pe + (size_t)p * E_;
  const float* yr = temb + (size_t)ty * E_;
  float v0 = tr[t] + pr[t] + yr[t];
  float v1 = tr[t + 256] + pr[t + 256] + yr[t + 256];
  float v2 = tr[t + 512] + pr[t + 512] + yr[t + 512];
  float m = block_sum256(v0 + v1 + v2) * (1.f / E_);
  float d0 = v0 - m, d1 = v1 - m, d2 = v2 - m;
  float var = block_sum256(d0 * d0 + d1 * d1 + d2 * d2) * (1.f / E_);
  float rs = 1.f / sqrtf(var + 1e-5f);
  size_t base = (size_t)row * E_;
  float r0 = d0 * rs * w[t] + b[t];
  float r1 = d1 * rs * w[t + 256] + b[t + 256];
  float r2 = d2 * rs * w[t + 512] + b[t + 512];
  out[base + t] = r0; out[base + t + 256] = r1; out[base + t + 512] = r2;
  short h, l;
  split_bf16(r0, h, l); ohi[base + t] = h; olo[base + t] = l;
  split_bf16(r1, h, l); ohi[base + t + 256] = h; olo[base + t + 256] = l;
  split_bf16(r2, h, l); ohi[base + t + 512] = h; olo[base + t + 512] = l;
}

// ---------------- LN (emits f32 + bf16 split planes) ----------------
__global__ __launch_bounds__(256) void ln_kernel(
    const float* __restrict__ in, const float* __restrict__ w,
    const float* __restrict__ b, float* __restrict__ out,
    short* __restrict__ ohi, short* __restrict__ olo) {
  int row = blockIdx.x;
  int t = threadIdx.x;
  const float* p = in + (size_t)row * E_;
  float v0 = p[t], v1 = p[t + 256], v2 = p[t + 512];
  float m = block_sum256(v0 + v1 + v2) * (1.f / E_);
  float d0 = v0 - m, d1 = v1 - m, d2 = v2 - m;
  float var = block_sum256(d0 * d0 + d1 * d1 + d2 * d2) * (1.f / E_);
  float rs = 1.f / sqrtf(var + 1e-5f);
  size_t base = (size_t)row * E_;
  float r0 = d0 * rs * w[t] + b[t];
  float r1 = d1 * rs * w[t + 256] + b[t + 256];
  float r2 = d2 * rs * w[t + 512] + b[t + 512];
  out[base + t] = r0; out[base + t + 256] = r1; out[base + t + 512] = r2;
  short h, l;
  split_bf16(r0, h, l); ohi[base + t] = h; olo[base + t] = l;
  split_bf16(r1, h, l); ohi[base + t + 256] = h; olo[base + t + 256] = l;
  split_bf16(r2, h, l); ohi[base + t + 512] = h; olo[base + t + 512] = l;
}

// ---------------- weight split: f32 -> (hi, lo) bf16 planes ----------------
__global__ __launch_bounds__(256) void split_kernel(
    const float* __restrict__ src, short* __restrict__ hi,
    short* __restrict__ lo, int n4) {
  int i = blockIdx.x * 256 + threadIdx.x;
  if (i >= n4) return;
  float4 v = ((const float4*)src)[i];
  short4 h, l;
  split_bf16(v.x, h.x, l.x);
  split_bf16(v.y, h.y, l.y);
  split_bf16(v.z, h.z, l.z);
  split_bf16(v.w, h.w, l.w);
  ((short4*)hi)[i] = h;
  ((short4*)lo)[i] = l;
}

// ---------------- deep-pipelined split-bf16 MFMA GEMM ----------------
// C = act(A @ W^T + bias (+R)).  A,W as bf16 hi/lo planes [M][K]/[N][K].
// Virtual K' = 3K (segments: Ahi*Whi | Ahi*Wlo | Alo*Whi).  BK=64 tiles,
// two K-halves per tile.  512 thr = 8 waves (2Mx4N), per-wave WMxWN out.
// Schedule per tile (4 phases): counted vmcnt(LA+LB) + raw s_barrier at
// p0/p2 only; half-tile stages spread p0..p3 with prefetch distance = 1
// tile; never vmcnt(0) in steady state.  LDS chunk-XOR swizzle
// (chunk' = chunk ^ ((row>>1)&3)) applied on BOTH stage-source and
// frag-read side; gload_lds dest stays linear.  setprio(1) around MFMA.
template <int BM, int BN, int ACT, int RES, int OSPLIT>
__global__ __launch_bounds__(512, (BM == 128 ? 4 : 2)) void gemm8p(
    const short* __restrict__ Ahi, const short* __restrict__ Alo,
    const short* __restrict__ Whi, const short* __restrict__ Wlo,
    const float* __restrict__ bias, const float* __restrict__ Rres,
    float* __restrict__ Cf, short* __restrict__ Chi, short* __restrict__ Clo,
    int M, int N, int K, int nx, int cpx) {
  constexpr int WM = BM / 2, WN = BN / 4;
  constexpr int MR = WM / 16, NR = WN / 16, MR2 = MR / 2;
  constexpr int LA = BM / 128, LB = BN / 128;
  constexpr int VM_ = LA + LB;

  __shared__ short lsA[2 * 2 * BM * 32];
  __shared__ short lsB[2 * 2 * BN * 32];

  const int t = threadIdx.x;
  const int wid = t >> 6, l = t & 63;
  const int li = l & 15, lh = l >> 4;
  const int wr = wid >> 2, wc = wid & 3;

  // XCD-aware bijective block swizzle (grid % 8 == 0 for all our shapes)
  int id = blockIdx.x;
  int id2 = (id & 7) * cpx + (id >> 3);
  const int n0 = (id2 % nx) * BN;
  const int m0 = (id2 / nx) * BM;

  const int segT = K >> 6;  // 64-K tiles per segment
  const int nt = 3 * segT;

  auto stA = [&](int bp2, int kh, const short* src, int kpos) {
#pragma unroll
    for (int i = 0; i < LA; ++i) {
      int slot = i * 512 + t;
      int row = slot >> 2;
      int c = (slot & 3) ^ ((row >> 1) & 3);
      gl2lds16(src + (size_t)(m0 + row) * K + kpos + kh * 32 + c * 8,
               lsA + (bp2 * 2 + kh) * (BM * 32) + i * 4096 + wid * 512);
    }
  };
  auto stB = [&](int bp2, int kh, const short* src, int kpos) {
#pragma unroll
    for (int i = 0; i < LB; ++i) {
      int slot = i * 512 + t;
      int row = slot >> 2;
      int c = (slot & 3) ^ ((row >> 1) & 3);
      gl2lds16(src + (size_t)(n0 + row) * K + kpos + kh * 32 + c * 8,
               lsB + (bp2 * 2 + kh) * (BN * 32) + i * 4096 + wid * 512);
    }
  };
  auto ldA = [&](int bp2, int kk, int mi) -> bf16x8 {
    int row = wr * WM + mi * 16 + li;
    int cp = lh ^ ((row >> 1) & 3);
    return *(const bf16x8*)(lsA + ((bp2 * 2 + kk) * BM + row) * 32 + cp * 8);
  };
  auto ldB = [&](int bp2, int kk, int ni) -> bf16x8 {
    int row = wc * WN + ni * 16 + li;
    int cp = lh ^ ((row >> 1) & 3);
    return *(const bf16x8*)(lsB + ((bp2 * 2 + kk) * BN + row) * 32 + cp * 8);
  };
  auto segp = [&](int kt, const short*& Ap, const short*& Wp, int& kpos) {
    int seg = kt / segT;
    kpos = (kt - seg * segT) * 64;
    Ap = (seg < 2) ? Ahi : Alo;
    Wp = (seg == 1) ? Wlo : Whi;
  };

  // preload bias BEFORE any staging so it is the oldest vmem op
  // (keeps the vmcnt ledger conservative-safe)
  float bv[NR];
#pragma unroll
  for (int ni = 0; ni < NR; ++ni) bv[ni] = bias[n0 + wc * WN + ni * 16 + li];

  // prologue: stage tile 0 (order A_k0, B_k0, A_k1, B_k1)
  {
    const short *Ap, *Wp;
    int kp;
    segp(0, Ap, Wp, kp);
    stA(0, 0, Ap, kp);
    stB(0, 0, Wp, kp);
    stA(0, 1, Ap, kp);
    stB(0, 1, Wp, kp);
  }

  f32x4 acc[MR][NR] = {};

  for (int kt = 0; kt < nt; ++kt) {
    const int bp = kt & 1;
    const bool pf = (kt + 1) < nt;
    const short *Ap1, *Wp1;
    int kp1;
    segp(pf ? kt + 1 : kt, Ap1, Wp1, kp1);

    bf16x8 bB[NR], aA[MR2];

    // ---------------- phase 0: kk=0, mi lo ----------------
    asm volatile("s_waitcnt vmcnt(%0)" ::"i"(VM_) : "memory");
    __builtin_amdgcn_s_barrier();
    if (pf) stA(bp ^ 1, 0, Ap1, kp1);
#pragma unroll
    for (int ni = 0; ni < NR; ++ni) bB[ni] = ldB(bp, 0, ni);
#pragma unroll
    for (int mi = 0; mi < MR2; ++mi) aA[mi] = ldA(bp, 0, mi);
    __builtin_amdgcn_s_setprio(1);
#pragma unroll
    for (int mi = 0; mi < MR2; ++mi)
#pragma unroll
      for (int ni = 0; ni < NR; ++ni)
        acc[mi][ni] = __builtin_amdgcn_mfma_f32_16x16x32_bf16(aA[mi], bB[ni], acc[mi][ni], 0, 0, 0);
    __builtin_amdgcn_s_setprio(0);

    // ---------------- phase 1: kk=0, mi hi ----------------
    if (pf) stB(bp ^ 1, 0, Wp1, kp1);
#pragma unroll
    for (int mi = 0; mi < MR2; ++mi) aA[mi] = ldA(bp, 0, MR2 + mi);
    __builtin_amdgcn_s_setprio(1);
#pragma unroll
    for (int mi = 0; mi < MR2; ++mi)
#pragma unroll
      for (int ni = 0; ni < NR; ++ni)
        acc[MR2 + mi][ni] = __builtin_amdgcn_mfma_f32_16x16x32_bf16(aA[mi], bB[ni], acc[MR2 + mi][ni], 0, 0, 0);
    __builtin_amdgcn_s_setprio(0);

    // ---------------- phase 2: kk=1, mi lo ----------------
    if (pf) {
      asm volatile("s_waitcnt vmcnt(%0)" ::"i"(VM_) : "memory");
    } else {
      asm volatile("s_waitcnt vmcnt(0)" ::: "memory");
    }
    __builtin_amdgcn_s_barrier();
    if (pf) stA(bp ^ 1, 1, Ap1, kp1);
#pragma unroll
    for (int ni = 0; ni < NR; ++ni) bB[ni] = ldB(bp, 1, ni);
#pragma unroll
    for (int mi = 0; mi < MR2; ++mi) aA[mi] = ldA(bp, 1, mi);
    __builtin_amdgcn_s_setprio(1);
#pragma unroll
    for (int mi = 0; mi < MR2; ++mi)
#pragma unroll
      for (int ni = 0; ni < NR; ++ni)
        acc[mi][ni] = __builtin_amdgcn_mfma_f32_16x16x32_bf16(aA[mi], bB[ni], acc[mi][ni], 0, 0, 0);
    __builtin_amdgcn_s_setprio(0);

    // ---------------- phase 3: kk=1, mi hi ----------------
    if (pf) stB(bp ^ 1, 1, Wp1, kp1);
#pragma unroll
    for (int mi = 0; mi < MR2; ++mi) aA[mi] = ldA(bp, 1, MR2 + mi);
    __builtin_amdgcn_s_setprio(1);
#pragma unroll
    for (int mi = 0; mi < MR2; ++mi)
#pragma unroll
      for (int ni = 0; ni < NR; ++ni)
        acc[MR2 + mi][ni] = __builtin_amdgcn_mfma_f32_16x16x32_bf16(aA[mi], bB[ni], acc[MR2 + mi][ni], 0, 0, 0);
    __builtin_amdgcn_s_setprio(0);
  }

  // ---------------- epilogue ----------------
#pragma unroll
  for (int mi = 0; mi < MR; ++mi) {
#pragma unroll
    for (int ni = 0; ni < NR; ++ni) {
      int col = n0 + wc * WN + ni * 16 + li;
      int row0 = m0 + wr * WM + mi * 16 + lh * 4;
      float bvv = bv[ni];
#pragma unroll
      for (int r = 0; r < 4; ++r) {
        int row = row0 + r;
        float v = acc[mi][ni][r] + bvv;
        if (RES) v += Rres[(size_t)row * N + col];
        if (ACT == 1) v = fmaxf(v, 0.f);
        if (ACT == 2) v = tanhf(v);
        if (OSPLIT) {
          short h2, l2;
          split_bf16(v, h2, l2);
          Chi[(size_t)row * N + col] = h2;
          Clo[(size_t)row * N + col] = l2;
        } else {
          Cf[(size_t)row * N + col] = v;
        }
      }
    }
  }
}

// ---------------- MFMA split-bf16 attention (unchanged from R6) ----------
__global__ __launch_bounds__(256, 2) void attn_kernel(
    const float* __restrict__ qkv, short* __restrict__ t1h,
    short* __restrict__ t1l) {
  __shared__ short lds[16384];
  const int qt = blockIdx.x, h = blockIdx.y, b = blockIdx.z;
  const int t = threadIdx.x;
  const int w = t >> 6, l = t & 63;
  const int li = l & 15, lh = l >> 4;

  short* kh = lds;
  short* kl = lds + 4096;
  short* ph = lds + 8192 + w * 2048;
  short* pl = ph + 1024;

  const int tok0 = b * S_ + qt * 64;

  bf16x8 qh[2], ql[2];
  {
    const float* qrow = qkv + (size_t)(tok0 + w * 16 + li) * 2304 + h * 64 + lh * 8;
#pragma unroll
    for (int s = 0; s < 2; s++) {
      float4 f0 = *(const float4*)(qrow + s * 32);
      float4 f1 = *(const float4*)(qrow + s * 32 + 4);
      float f[8] = {f0.x, f0.y, f0.z, f0.w, f1.x, f1.y, f1.z, f1.w};
      bf16x8 hv, lv;
#pragma unroll
      for (int j = 0; j < 8; j++) {
        short hs, ls2;
        split_bf16(f[j], hs, ls2);
        hv[j] = hs; lv[j] = ls2;
      }
      qh[s] = hv; ql[s] = lv;
    }
  }

  const int skk = t >> 2, sd0 = (t & 3) * 16;

  f32x4 acc[16] = {};

  const float* kbase = qkv + (size_t)(b * S_) * 2304 + 768 + h * 64;
#pragma unroll
  for (int c = 0; c < 4; c++) {
    __syncthreads();
    {
      const float* src = kbase + (size_t)(c * 64 + skk) * 2304 + sd0;
#pragma unroll
      for (int i = 0; i < 4; i++) {
        float4 f = *(const float4*)(src + i * 4);
        int d = sd0 + i * 4;
        short4 hv, lv;
        split_bf16(f.x, hv.x, lv.x);
        split_bf16(f.y, hv.y, lv.y);
        split_bf16(f.z, hv.z, lv.z);
        split_bf16(f.w, hv.w, lv.w);
        int off = skk * 64 + ((((d >> 3) ^ (skk & 7)) & 7) << 3) + (d & 7);
        *(short4*)(kh + off) = hv;
        *(short4*)(kl + off) = lv;
      }
    }
    __syncthreads();
#pragma unroll
    for (int nn = 0; nn < 4; nn++) {
      const int krow = nn * 16 + li;
#pragma unroll
      for (int s = 0; s < 2; s++) {
        const int off = krow * 64 + ((((s * 4 + lh) ^ (li & 7)) & 7) << 3);
        bf16x8 bh = *(const bf16x8*)(kh + off);
        bf16x8 bl = *(const bf16x8*)(kl + off);
        acc[c * 4 + nn] = __builtin_amdgcn_mfma_f32_16x16x32_bf16(qh[s], bh, acc[c * 4 + nn], 0, 0, 0);
        acc[c * 4 + nn] = __builtin_amdgcn_mfma_f32_16x16x32_bf16(qh[s], bl, acc[c * 4 + nn], 0, 0, 0);
        acc[c * 4 + nn] = __builtin_amdgcn_mfma_f32_16x16x32_bf16(ql[s], bh, acc[c * 4 + nn], 0, 0, 0);
      }
    }
  }

  float rs_[4];
#pragma unroll
  for (int r = 0; r < 4; r++) {
    float m = -3.4e38f;
#pragma unroll
    for (int fi = 0; fi < 16; fi++) m = fmaxf(m, acc[fi][r]);
#pragma unroll
    for (int off = 8; off; off >>= 1) m = fmaxf(m, __shfl_xor(m, off));
    float sum = 0.f;
#pragma unroll
    for (int fi = 0; fi < 16; fi++) {
      float p = expf((acc[fi][r] - m) * 0.125f);
      acc[fi][r] = p;
      sum += p;
    }
#pragma unroll
    for (int off = 8; off; off >>= 1) sum += __shfl_xor(sum, off);
    rs_[r] = sum;
  }

  f32x4 oacc[4] = {};
  const float* vbase = qkv + (size_t)(b * S_) * 2304 + 1536 + h * 64;
#pragma unroll
  for (int c = 0; c < 4; c++) {
    __syncthreads();
    {
      const float* src = vbase + (size_t)(c * 64 + skk) * 2304 + sd0;
#pragma unroll
      for (int i = 0; i < 4; i++) {
        float4 f = *(const float4*)(src + i * 4);
        float fv[4] = {f.x, f.y, f.z, f.w};
#pragma unroll
        for (int j = 0; j < 4; j++) {
          int d = sd0 + i * 4 + j;
          short hs, ls2;
          split_bf16(fv[j], hs, ls2);
          int sw = (d & 7) ^ ((d >> 3) & 7);
          int off = d * 64 + ((((skk >> 3) ^ sw) & 7) << 3) + (skk & 7);
          kh[off] = hs;
          kl[off] = ls2;
        }
      }
    }
#pragma unroll
    for (int nn = 0; nn < 4; nn++) {
#pragma unroll
      for (int r = 0; r < 4; r++) {
        const int q = lh * 4 + r;
        const int keyl = li + 16 * nn;
        short hs, ls2;
        split_bf16(acc[c * 4 + nn][r], hs, ls2);
        const int off = q * 64 + ((((keyl >> 3) ^ (q & 7)) & 7) << 3) + (keyl & 7);
        ph[off] = hs;
        pl[off] = ls2;
      }
    }
    __syncthreads();
    bf16x8 pah[2], pal[2];
#pragma unroll
    for (int s = 0; s < 2; s++) {
      const int off = li * 64 + ((((s * 4 + lh) ^ (li & 7)) & 7) << 3);
      pah[s] = *(const bf16x8*)(ph + off);
      pal[s] = *(const bf16x8*)(pl + off);
    }
#pragma unroll
    for (int dn = 0; dn < 4; dn++) {
      const int drow = dn * 16 + li;
      const int sw = ((drow & 7) ^ ((drow >> 3) & 7)) & 7;
#pragma unroll
      for (int s = 0; s < 2; s++) {
        const int off = drow * 64 + ((((s * 4 + lh) ^ sw) & 7) << 3);
        bf16x8 vh = *(const bf16x8*)(kh + off);
        bf16x8 vl = *(const bf16x8*)(kl + off);
        oacc[dn] = __builtin_amdgcn_mfma_f32_16x16x32_bf16(pah[s], vh, oacc[dn], 0, 0, 0);
        oacc[dn] = __builtin_amdgcn_mfma_f32_16x16x32_bf16(pah[s], vl, oacc[dn], 0, 0, 0);
        oacc[dn] = __builtin_amdgcn_mfma_f32_16x16x32_bf16(pal[s], vh, oacc[dn], 0, 0, 0);
      }
    }
  }

  float rinv[4];
#pragma unroll
  for (int r = 0; r < 4; r++) rinv[r] = 1.f / rs_[r];
#pragma unroll
  for (int dn = 0; dn < 4; dn++) {
#pragma unroll
    for (int r = 0; r < 4; r++) {
      float v = oacc[dn][r] * rinv[r];
      short hs, ls2;
      split_bf16(v, hs, ls2);
      size_t oidx = (size_t)(tok0 + w * 16 + lh * 4 + r) * E_ + h * 64 + dn * 16 + li;
      t1h[oidx] = hs;
      t1l[oidx] = ls2;
    }
  }
}

// ---------------- cosine similarity ----------------
__global__ __launch_bounds__(256) void cos_kernel(
    const float* __restrict__ a, const float* __restrict__ o,
    float* __restrict__ cosv) {
  int row = blockIdx.x;
  int t = threadIdx.x;
  const float* ar = a + (size_t)row * E_;
  const float* orr = o + (size_t)row * E_;
  float d = 0.f, na = 0.f, nb = 0.f;
#pragma unroll
  for (int j = 0; j < 3; j++) {
    float av = ar[t + 256 * j], ov = orr[t + 256 * j];
    d = fmaf(av, ov, d);
    na = fmaf(av, av, na);
    nb = fmaf(ov, ov, nb);
  }
  d = block_sum256(d);
  na = block_sum256(na);
  nb = block_sum256(nb);
  if (t == 0) cosv[row] = d / fmaxf(sqrtf(na) * sqrtf(nb), 1e-8f);
}

// ---------------- top-k mark (iterative argmax, ties -> lowest index) --------
__device__ void topk_mark(float v, int keep, float* vals, float* bits) {
  int t = threadIdx.x;
  __shared__ float wv[4];
  __shared__ int wi[4];
  vals[t] = v;
  __syncthreads();
  for (int it = 0; it < keep; ++it) {
    float mv = vals[t];
    int mi = t;
#pragma unroll
    for (int off = 32; off; off >>= 1) {
      float ov = __shfl_down(mv, off);
      int oi = __shfl_down(mi, off);
      if (ov > mv || (ov == mv && oi < mi)) { mv = ov; mi = oi; }
    }
    if ((t & 63) == 0) { wv[t >> 6] = mv; wi[t >> 6] = mi; }
    __syncthreads();
    if (t == 0) {
      float bv = wv[0]; int bi = wi[0];
      for (int w = 1; w < 4; ++w)
        if (wv[w] > bv || (wv[w] == bv && wi[w] < bi)) { bv = wv[w]; bi = wi[w]; }
      bits[bi] += 1.f;
      vals[bi] = -INFINITY;
    }
    __syncthreads();
  }
}

// ---------------- final selection ----------------
__global__ __launch_bounds__(256) void select_kernel(
    const float* __restrict__ cosv, const int* __restrict__ typ,
    const float* __restrict__ gh, const float* __restrict__ gt,
    float* __restrict__ out) {
  __shared__ float vals[256];
  __shared__ float bits[256];
  int b = blockIdx.x, t = threadIdx.x;
  int idx = b * 256 + t;
  int ty = typ[idx];
  float c = cosv[idx];
  bits[t] = 0.f;
  float eh = (ty == 1) ? expf(c) : 0.f;
  float sh = block_sum256(eh);
  float glh = (ty == 1) ? (logf(eh / sh) + gh[idx]) : NEGV;
  topk_mark(glh, 64, vals, bits);
  float et = (ty == 2) ? expf(c) : 0.f;
  float st = block_sum256(et);
  float glt = (ty == 2) ? (logf(1.f - et / st) + gt[idx]) : NEGV;
  topk_mark(glt, 63, vals, bits);
  __syncthreads();
  out[idx] = bits[t];
}

// ---------------- host-side launchers ----------------
template <int BM, int BN, int ACT, int RES, int OSPLIT>
static void launch8p(const short* Ahi, const short* Alo, const short* Whi,
                     const short* Wlo, const float* bias, const float* R,
                     float* Cf, short* Chi, short* Clo, int M, int N, int K,
                     hipStream_t s) {
  int nx = N / BN, ny = M / BM;
  int nwg = nx * ny;
  gemm8p<BM, BN, ACT, RES, OSPLIT><<<nwg, 512, 0, s>>>(
      Ahi, Alo, Whi, Wlo, bias, R, Cf, Chi, Clo, M, N, K, nx, nwg / 8);
}

extern "C" void kernel_launch(void* const* d_in, const int* in_sizes, int n_in,
                              void* d_out, int out_size, void* d_ws,
                              size_t ws_size, hipStream_t stream) {
  const float* tok = (const float*)d_in[0];
  const int* pos = (const int*)d_in[2];
  const int* typ = (const int*)d_in[3];
  const float* gh = (const float*)d_in[4];
  const float* gt = (const float*)d_in[5];
  const float* pe = (const float*)d_in[6];
  const float* temb = (const float*)d_in[7];
  const float* ln_w = (const float*)d_in[8];
  const float* ln_b = (const float*)d_in[9];
  const float* dense_w = (const float*)d_in[10];
  const float* dense_b = (const float*)d_in[11];
  const float* qkv_w = (const float*)d_in[12];
  const float* qkv_b = (const float*)d_in[13];
  const float* out_w = (const float*)d_in[14];
  const float* out_b = (const float*)d_in[15];
  const float* ln1_w = (const float*)d_in[16];
  const float* ln1_b = (const float*)d_in[17];
  const float* lin1_w = (const float*)d_in[18];
  const float* lin1_b = (const float*)d_in[19];
  const float* lin2_w = (const float*)d_in[20];
  const float* lin2_b = (const float*)d_in[21];
  const float* ln2_w = (const float*)d_in[22];
  const float* ln2_b = (const float*)d_in[23];

  const int M = B_ * S_;
  const size_t NX = (size_t)M * E_;
  const size_t NQKV = (size_t)M * 3 * E_;
  const size_t NFF = (size_t)M * FF_;

  const size_t oQ = 0;
  const size_t oO = oQ + 2 * (size_t)3 * E_ * E_;
  const size_t oL1 = oO + 2 * (size_t)E_ * E_;
  const size_t oL2 = oL1 + 2 * (size_t)FF_ * E_;
  const size_t oD = oL2 + 2 * (size_t)E_ * FF_;
  const size_t WTOT = oD + (size_t)E_ * E_;

  float* ws = (float*)d_ws;
  float* x = ws;
  float* t2 = x + NX;
  float* shared = t2 + NX;
  short* x_hi = (short*)(shared + NQKV);
  short* x_lo = x_hi + NX;
  short* t1_hi = x_lo + NX;
  short* t1_lo = t1_hi + NX;
  short* w_hi = t1_lo + NX;
  short* w_lo = w_hi + WTOT;
  float* cosb = (float*)(w_lo + WTOT);

  short* big_hi = (short*)shared;
  short* big_lo = big_hi + NFF;

  // ---- split weights into bf16 hi/lo planes ----
  {
    int n4;
    n4 = (int)(2 * 3 * E_ * E_ / 4);
    split_kernel<<<(n4 + 255) / 256, 256, 0, stream>>>(qkv_w, w_hi + oQ, w_lo + oQ, n4);
    n4 = (int)(2 * E_ * E_ / 4);
    split_kernel<<<(n4 + 255) / 256, 256, 0, stream>>>(out_w, w_hi + oO, w_lo + oO, n4);
    n4 = (int)(2 * FF_ * E_ / 4);
    split_kernel<<<(n4 + 255) / 256, 256, 0, stream>>>(lin1_w, w_hi + oL1, w_lo + oL1, n4);
    n4 = (int)(2 * E_ * FF_ / 4);
    split_kernel<<<(n4 + 255) / 256, 256, 0, stream>>>(lin2_w, w_hi + oL2, w_lo + oL2, n4);
    n4 = (int)(E_ * E_ / 4);
    split_kernel<<<(n4 + 255) / 256, 256, 0, stream>>>(dense_w, w_hi + oD, w_lo + oD, n4);
  }

  // ---- embed + LN ----
  embed_ln_kernel<<<M, 256, 0, stream>>>(tok, pos, typ, pe, temb, ln_w, ln_b,
                                         x, x_hi, x_lo);

  for (int l = 0; l < L_; l++) {
    const size_t wq = oQ + (size_t)l * 3 * E_ * E_;
    const size_t wo = oO + (size_t)l * E_ * E_;
    const size_t w1 = oL1 + (size_t)l * FF_ * E_;
    const size_t w2 = oL2 + (size_t)l * E_ * FF_;
    // qkv = x @ qkv_w^T + b  -> f32 (shared)
    launch8p<256, 256, 0, 0, 0>(x_hi, x_lo, w_hi + wq, w_lo + wq,
                                qkv_b + (size_t)l * 3 * E_, nullptr, shared,
                                nullptr, nullptr, M, 3 * E_, E_, stream);
    // attention -> t1 splits (MFMA)
    attn_kernel<<<dim3(4, H_, B_), 256, 0, stream>>>(shared, t1_hi, t1_lo);
    // t2 = x + t1 @ out_w^T + b
    launch8p<128, 128, 0, 1, 0>(t1_hi, t1_lo, w_hi + wo, w_lo + wo,
                                out_b + (size_t)l * E_, x, t2, nullptr, nullptr,
                                M, E_, E_, stream);
    // x = LN(t2)
    ln_kernel<<<M, 256, 0, stream>>>(t2, ln1_w + (size_t)l * E_,
                                     ln1_b + (size_t)l * E_, x, x_hi, x_lo);
    // big = relu(x @ lin1_w^T + b) -> splits
    launch8p<256, 256, 1, 0, 1>(x_hi, x_lo, w_hi + w1, w_lo + w1,
                                lin1_b + (size_t)l * FF_, nullptr, nullptr,
                                big_hi, big_lo, M, FF_, E_, stream);
    // t2 = x + big @ lin2_w^T + b
    launch8p<128, 128, 0, 1, 0>(big_hi, big_lo, w_hi + w2, w_lo + w2,
                                lin2_b + (size_t)l * E_, x, t2, nullptr,
                                nullptr, M, E_, FF_, stream);
    // x = LN(t2)
    ln_kernel<<<M, 256, 0, stream>>>(t2, ln2_w + (size_t)l * E_,
                                     ln2_b + (size_t)l * E_, x, x_hi, x_lo);
  }

  // final LN -> splits into t1 planes
  ln_kernel<<<M, 256, 0, stream>>>(x, ln_w, ln_b, t2, t1_hi, t1_lo);
  // dense: tanh(t1 @ dense_w^T + b) -> f32 (shared region)
  launch8p<128, 128, 2, 0, 0>(t1_hi, t1_lo, w_hi + oD, w_lo + oD, dense_b,
                              nullptr, shared, nullptr, nullptr, M, E_, E_,
                              stream);
  // cos
  cos_kernel<<<M, 256, 0, stream>>>(tok, shared, cosb);
  // selection
  select_kernel<<<B_, 256, 0, stream>>>(cosb, typ, gh, gt, (float*)d_out);
}

// Round 8
// 934.304 us; speedup vs baseline: 1.4185x; 1.4185x over previous
//
#include <hip/hip_runtime.h>
#include <math.h>

#define B_ 32
#define S_ 256
#define E_ 768
#define H_ 12
#define L_ 2
#define FF_ 2048
#define NEGV -1e30f

typedef __attribute__((ext_vector_type(8))) short bf16x8;
typedef __attribute__((ext_vector_type(4))) float f32x4;

// ---------- bf16 split helpers ----------
__device__ __forceinline__ short bf16_rne(float x) {
  unsigned u = __float_as_uint(x);
  u += 0x7fffu + ((u >> 16) & 1u);
  return (short)(u >> 16);
}
__device__ __forceinline__ float bf16_to_f32(short h) {
  return __uint_as_float(((unsigned)(unsigned short)h) << 16);
}
__device__ __forceinline__ void split_bf16(float v, short& h, short& l) {
  h = bf16_rne(v);
  l = bf16_rne(v - bf16_to_f32(h));
}

__device__ __forceinline__ void gl2lds16(const short* g, short* s) {
  __builtin_amdgcn_global_load_lds((const __attribute__((address_space(1))) void*)g,
                                   (__attribute__((address_space(3))) void*)s, 16, 0, 0);
}

// ---------------- block-wide sum over 256 threads ----------------
__device__ __forceinline__ float block_sum256(float v) {
  __shared__ float sh[4];
  int lane = threadIdx.x & 63, w = threadIdx.x >> 6;
#pragma unroll
  for (int off = 32; off; off >>= 1) v += __shfl_down(v, off);
  if (lane == 0) sh[w] = v;
  __syncthreads();
  float tot = sh[0] + sh[1] + sh[2] + sh[3];
  __syncthreads();
  return tot;
}

// ---------------- embed + LN (emits f32 + bf16 split planes) ----------------
__global__ __launch_bounds__(256) void embed_ln_kernel(
    const float* __restrict__ tok, const int* __restrict__ pos,
    const int* __restrict__ typ, const float* __restrict__ pe,
    const float* __restrict__ temb, const float* __restrict__ w,
    const float* __restrict__ b, float* __restrict__ out,
    short* __restrict__ ohi, short* __restrict__ olo) {
  int row = blockIdx.x;
  int t = threadIdx.x;
  int p = pos[row], ty = typ[row];
  const float* tr = tok + (size_t)row * E_;
  const float* pr = pe + (size_t)p * E_;
  const float* yr = temb + (size_t)ty * E_;
  float v0 = tr[t] + pr[t] + yr[t];
  float v1 = tr[t + 256] + pr[t + 256] + yr[t + 256];
  float v2 = tr[t + 512] + pr[t + 512] + yr[t + 512];
  float m = block_sum256(v0 + v1 + v2) * (1.f / E_);
  float d0 = v0 - m, d1 = v1 - m, d2 = v2 - m;
  float var = block_sum256(d0 * d0 + d1 * d1 + d2 * d2) * (1.f / E_);
  float rs = 1.f / sqrtf(var + 1e-5f);
  size_t base = (size_t)row * E_;
  float r0 = d0 * rs * w[t] + b[t];
  float r1 = d1 * rs * w[t + 256] + b[t + 256];
  float r2 = d2 * rs * w[t + 512] + b[t + 512];
  out[base + t] = r0; out[base + t + 256] = r1; out[base + t + 512] = r2;
  short h, l;
  split_bf16(r0, h, l); ohi[base + t] = h; olo[base + t] = l;
  split_bf16(r1, h, l); ohi[base + t + 256] = h; olo[base + t + 256] = l;
  split_bf16(r2, h, l); ohi[base + t + 512] = h; olo[base + t + 512] = l;
}

// ---------------- LN (emits f32 + bf16 split planes) ----------------
__global__ __launch_bounds__(256) void ln_kernel(
    const float* __restrict__ in, const float* __restrict__ w,
    const float* __restrict__ b, float* __restrict__ out,
    short* __restrict__ ohi, short* __restrict__ olo) {
  int row = blockIdx.x;
  int t = threadIdx.x;
  const float* p = in + (size_t)row * E_;
  float v0 = p[t], v1 = p[t + 256], v2 = p[t + 512];
  float m = block_sum256(v0 + v1 + v2) * (1.f / E_);
  float d0 = v0 - m, d1 = v1 - m, d2 = v2 - m;
  float var = block_sum256(d0 * d0 + d1 * d1 + d2 * d2) * (1.f / E_);
  float rs = 1.f / sqrtf(var + 1e-5f);
  size_t base = (size_t)row * E_;
  float r0 = d0 * rs * w[t] + b[t];
  float r1 = d1 * rs * w[t + 256] + b[t + 256];
  float r2 = d2 * rs * w[t + 512] + b[t + 512];
  out[base + t] = r0; out[base + t + 256] = r1; out[base + t + 512] = r2;
  short h, l;
  split_bf16(r0, h, l); ohi[base + t] = h; olo[base + t] = l;
  split_bf16(r1, h, l); ohi[base + t + 256] = h; olo[base + t + 256] = l;
  split_bf16(r2, h, l); ohi[base + t + 512] = h; olo[base + t + 512] = l;
}

// ---------------- weight split: f32 -> (hi, lo) bf16 planes ----------------
__global__ __launch_bounds__(256) void split_kernel(
    const float* __restrict__ src, short* __restrict__ hi,
    short* __restrict__ lo, int n4) {
  int i = blockIdx.x * 256 + threadIdx.x;
  if (i >= n4) return;
  float4 v = ((const float4*)src)[i];
  short4 h, l;
  split_bf16(v.x, h.x, l.x);
  split_bf16(v.y, h.y, l.y);
  split_bf16(v.z, h.z, l.z);
  split_bf16(v.w, h.w, l.w);
  ((short4*)hi)[i] = h;
  ((short4*)lo)[i] = l;
}

// ---------------- deep-pipelined split-bf16 MFMA GEMM (R6 structure + dbuf) --
// C = act(A @ W^T + bias (+R)).  A,W as bf16 hi/lo planes [M][K]/[N][K].
// 128x128 tile, BK=32, 256 thr = 4 waves (2x2 of 64x64), joint 3-pass:
// acc += Ahi*Whi + Ahi*Wlo + Alo*Whi  (each frag quad feeds 3 MFMAs, 3:1
// MFMA:ds_read).  DOUBLE-buffered LDS (2 x 32KB), raw s_barrier (no drain),
// counted s_waitcnt vmcnt(8) issued AFTER next-tile stage -> 8 loads always
// in flight across the barrier; vmcnt(0) only on the last tile.
// Per step: { B1 ; stage(buf^1, s+1) ; vmcnt(8) ; B2 ; frag reads + 48 MFMA }.
template <int ACT, int RES, int OSPLIT>
__global__ __launch_bounds__(256, 2) void gemm_dp(
    const short* __restrict__ Ahi, const short* __restrict__ Alo,
    const short* __restrict__ Whi, const short* __restrict__ Wlo,
    const float* __restrict__ bias, const float* __restrict__ Rres,
    float* __restrict__ Cf, short* __restrict__ Chi, short* __restrict__ Clo,
    int M, int N, int K, int nx, int cpx) {
  __shared__ short lds[2 * 16384];  // dbuf x (4 planes x 4096 shorts)
  const int t = threadIdx.x;
  const int l = t & 63;
  const int w = t >> 6;
  // XCD-aware bijective block swizzle (nwg % 8 == 0 for all shapes here)
  int id = blockIdx.x;
  int id2 = (id & 7) * cpx + (id >> 3);
  const int n0 = (id2 % nx) * 128, m0 = (id2 / nx) * 128;
  const int wm = (w >> 1) * 64, wn = (w & 1) * 64;

  // ---- staging: per-lane swizzled global source, linear LDS dest ----
  const int g_kb = (l & 3) ^ ((l >> 3) & 3);  // lane-constant source swizzle
  const int r0 = w * 16 + (l >> 2);
  const int r1 = r0 + 64;
  const size_t aof0 = (size_t)(m0 + r0) * K + g_kb * 8;
  const size_t aof1 = (size_t)(m0 + r1) * K + g_kb * 8;
  const size_t wof0 = (size_t)(n0 + r0) * K + g_kb * 8;
  const size_t wof1 = (size_t)(n0 + r1) * K + g_kb * 8;
  const short* pAh0 = Ahi + aof0; const short* pAh1 = Ahi + aof1;
  const short* pAl0 = Alo + aof0; const short* pAl1 = Alo + aof1;
  const short* pWh0 = Whi + wof0; const short* pWh1 = Whi + wof1;
  const short* pWl0 = Wlo + wof0; const short* pWl1 = Wlo + wof1;

  // ---- frag-read addresses (lane-constant swizzle) ----
  const int kb_r = ((l >> 4) ^ ((l >> 1) & 3)) * 8;
  const short* ra = lds + (wm + (l & 15)) * 32 + kb_r;
  const short* rb = lds + (wn + (l & 15)) * 32 + kb_r;

  f32x4 acc[4][4] = {};
  const int ns = K >> 5;

  auto stage = [&](int buf, int k0) {
    short* base = lds + buf * 16384;
    gl2lds16(pAh0 + k0, base + w * 512);
    gl2lds16(pAh1 + k0, base + (4 + w) * 512);
    gl2lds16(pAl0 + k0, base + 4096 + w * 512);
    gl2lds16(pAl1 + k0, base + 4096 + (4 + w) * 512);
    gl2lds16(pWh0 + k0, base + 8192 + w * 512);
    gl2lds16(pWh1 + k0, base + 8192 + (4 + w) * 512);
    gl2lds16(pWl0 + k0, base + 12288 + w * 512);
    gl2lds16(pWl1 + k0, base + 12288 + (4 + w) * 512);
  };

  // prologue: stage tile 0 into buf 0
  stage(0, 0);

  for (int s = 0; s < ns; ++s) {
    const int bp = s & 1;
    // B1: all waves finished reading buf bp^1 (during step s-1) before we
    // overwrite it below.
    __builtin_amdgcn_s_barrier();
    if (s + 1 < ns) {
      stage(bp ^ 1, (s + 1) * 32);
      __builtin_amdgcn_sched_barrier(0);
      asm volatile("s_waitcnt vmcnt(8)" ::: "memory");  // waits tile-s loads only
    } else {
      __builtin_amdgcn_sched_barrier(0);
      asm volatile("s_waitcnt vmcnt(0)" ::: "memory");
    }
    // B2: publish buf bp to all waves
    __builtin_amdgcn_s_barrier();

    const short* rab = ra + bp * 16384;
    const short* rbb = rb + bp * 16384;
    bf16x8 ah[4], al[4], bh[4], bl[4];
#pragma unroll
    for (int i = 0; i < 4; i++) {
      ah[i] = *(const bf16x8*)(rab + i * 512);
      al[i] = *(const bf16x8*)(rab + 4096 + i * 512);
      bh[i] = *(const bf16x8*)(rbb + 8192 + i * 512);
      bl[i] = *(const bf16x8*)(rbb + 12288 + i * 512);
    }
    __builtin_amdgcn_s_setprio(1);
#pragma unroll
    for (int mi = 0; mi < 4; mi++)
#pragma unroll
      for (int ni = 0; ni < 4; ni++) {
        acc[mi][ni] = __builtin_amdgcn_mfma_f32_16x16x32_bf16(ah[mi], bh[ni], acc[mi][ni], 0, 0, 0);
        acc[mi][ni] = __builtin_amdgcn_mfma_f32_16x16x32_bf16(ah[mi], bl[ni], acc[mi][ni], 0, 0, 0);
        acc[mi][ni] = __builtin_amdgcn_mfma_f32_16x16x32_bf16(al[mi], bh[ni], acc[mi][ni], 0, 0, 0);
      }
    __builtin_amdgcn_s_setprio(0);
  }

  // ---- epilogue: D[row = (l>>4)*4+r, col = l&15] per 16x16 frag ----
  const int col_l = l & 15;
  const int row_l = (l >> 4) * 4;
#pragma unroll
  for (int mi = 0; mi < 4; mi++) {
#pragma unroll
    for (int ni = 0; ni < 4; ni++) {
      int col = n0 + wn + ni * 16 + col_l;
      float bv = bias[col];
#pragma unroll
      for (int r = 0; r < 4; r++) {
        int row = m0 + wm + mi * 16 + row_l + r;
        float v = acc[mi][ni][r] + bv;
        if (RES) v += Rres[(size_t)row * N + col];
        if (ACT == 1) v = fmaxf(v, 0.f);
        if (ACT == 2) v = tanhf(v);
        if (OSPLIT) {
          short h2, l2;
          split_bf16(v, h2, l2);
          Chi[(size_t)row * N + col] = h2;
          Clo[(size_t)row * N + col] = l2;
        } else {
          Cf[(size_t)row * N + col] = v;
        }
      }
    }
  }
}

// ---------------- MFMA split-bf16 attention (unchanged from R6) ----------
__global__ __launch_bounds__(256, 2) void attn_kernel(
    const float* __restrict__ qkv, short* __restrict__ t1h,
    short* __restrict__ t1l) {
  __shared__ short lds[16384];
  const int qt = blockIdx.x, h = blockIdx.y, b = blockIdx.z;
  const int t = threadIdx.x;
  const int w = t >> 6, l = t & 63;
  const int li = l & 15, lh = l >> 4;

  short* kh = lds;
  short* kl = lds + 4096;
  short* ph = lds + 8192 + w * 2048;
  short* pl = ph + 1024;

  const int tok0 = b * S_ + qt * 64;

  bf16x8 qh[2], ql[2];
  {
    const float* qrow = qkv + (size_t)(tok0 + w * 16 + li) * 2304 + h * 64 + lh * 8;
#pragma unroll
    for (int s = 0; s < 2; s++) {
      float4 f0 = *(const float4*)(qrow + s * 32);
      float4 f1 = *(const float4*)(qrow + s * 32 + 4);
      float f[8] = {f0.x, f0.y, f0.z, f0.w, f1.x, f1.y, f1.z, f1.w};
      bf16x8 hv, lv;
#pragma unroll
      for (int j = 0; j < 8; j++) {
        short hs, ls2;
        split_bf16(f[j], hs, ls2);
        hv[j] = hs; lv[j] = ls2;
      }
      qh[s] = hv; ql[s] = lv;
    }
  }

  const int skk = t >> 2, sd0 = (t & 3) * 16;

  f32x4 acc[16] = {};

  const float* kbase = qkv + (size_t)(b * S_) * 2304 + 768 + h * 64;
#pragma unroll
  for (int c = 0; c < 4; c++) {
    __syncthreads();
    {
      const float* src = kbase + (size_t)(c * 64 + skk) * 2304 + sd0;
#pragma unroll
      for (int i = 0; i < 4; i++) {
        float4 f = *(const float4*)(src + i * 4);
        int d = sd0 + i * 4;
        short4 hv, lv;
        split_bf16(f.x, hv.x, lv.x);
        split_bf16(f.y, hv.y, lv.y);
        split_bf16(f.z, hv.z, lv.z);
        split_bf16(f.w, hv.w, lv.w);
        int off = skk * 64 + ((((d >> 3) ^ (skk & 7)) & 7) << 3) + (d & 7);
        *(short4*)(kh + off) = hv;
        *(short4*)(kl + off) = lv;
      }
    }
    __syncthreads();
#pragma unroll
    for (int nn = 0; nn < 4; nn++) {
      const int krow = nn * 16 + li;
#pragma unroll
      for (int s = 0; s < 2; s++) {
        const int off = krow * 64 + ((((s * 4 + lh) ^ (li & 7)) & 7) << 3);
        bf16x8 bh = *(const bf16x8*)(kh + off);
        bf16x8 bl = *(const bf16x8*)(kl + off);
        acc[c * 4 + nn] = __builtin_amdgcn_mfma_f32_16x16x32_bf16(qh[s], bh, acc[c * 4 + nn], 0, 0, 0);
        acc[c * 4 + nn] = __builtin_amdgcn_mfma_f32_16x16x32_bf16(qh[s], bl, acc[c * 4 + nn], 0, 0, 0);
        acc[c * 4 + nn] = __builtin_amdgcn_mfma_f32_16x16x32_bf16(ql[s], bh, acc[c * 4 + nn], 0, 0, 0);
      }
    }
  }

  float rs_[4];
#pragma unroll
  for (int r = 0; r < 4; r++) {
    float m = -3.4e38f;
#pragma unroll
    for (int fi = 0; fi < 16; fi++) m = fmaxf(m, acc[fi][r]);
#pragma unroll
    for (int off = 8; off; off >>= 1) m = fmaxf(m, __shfl_xor(m, off));
    float sum = 0.f;
#pragma unroll
    for (int fi = 0; fi < 16; fi++) {
      float p = expf((acc[fi][r] - m) * 0.125f);
      acc[fi][r] = p;
      sum += p;
    }
#pragma unroll
    for (int off = 8; off; off >>= 1) sum += __shfl_xor(sum, off);
    rs_[r] = sum;
  }

  f32x4 oacc[4] = {};
  const float* vbase = qkv + (size_t)(b * S_) * 2304 + 1536 + h * 64;
#pragma unroll
  for (int c = 0; c < 4; c++) {
    __syncthreads();
    {
      const float* src = vbase + (size_t)(c * 64 + skk) * 2304 + sd0;
#pragma unroll
      for (int i = 0; i < 4; i++) {
        float4 f = *(const float4*)(src + i * 4);
        float fv[4] = {f.x, f.y, f.z, f.w};
#pragma unroll
        for (int j = 0; j < 4; j++) {
          int d = sd0 + i * 4 + j;
          short hs, ls2;
          split_bf16(fv[j], hs, ls2);
          int sw = (d & 7) ^ ((d >> 3) & 7);
          int off = d * 64 + ((((skk >> 3) ^ sw) & 7) << 3) + (skk & 7);
          kh[off] = hs;
          kl[off] = ls2;
        }
      }
    }
#pragma unroll
    for (int nn = 0; nn < 4; nn++) {
#pragma unroll
      for (int r = 0; r < 4; r++) {
        const int q = lh * 4 + r;
        const int keyl = li + 16 * nn;
        short hs, ls2;
        split_bf16(acc[c * 4 + nn][r], hs, ls2);
        const int off = q * 64 + ((((keyl >> 3) ^ (q & 7)) & 7) << 3) + (keyl & 7);
        ph[off] = hs;
        pl[off] = ls2;
      }
    }
    __syncthreads();
    bf16x8 pah[2], pal[2];
#pragma unroll
    for (int s = 0; s < 2; s++) {
      const int off = li * 64 + ((((s * 4 + lh) ^ (li & 7)) & 7) << 3);
      pah[s] = *(const bf16x8*)(ph + off);
      pal[s] = *(const bf16x8*)(pl + off);
    }
#pragma unroll
    for (int dn = 0; dn < 4; dn++) {
      const int drow = dn * 16 + li;
      const int sw = ((drow & 7) ^ ((drow >> 3) & 7)) & 7;
#pragma unroll
      for (int s = 0; s < 2; s++) {
        const int off = drow * 64 + ((((s * 4 + lh) ^ sw) & 7) << 3);
        bf16x8 vh = *(const bf16x8*)(kh + off);
        bf16x8 vl = *(const bf16x8*)(kl + off);
        oacc[dn] = __builtin_amdgcn_mfma_f32_16x16x32_bf16(pah[s], vh, oacc[dn], 0, 0, 0);
        oacc[dn] = __builtin_amdgcn_mfma_f32_16x16x32_bf16(pah[s], vl, oacc[dn], 0, 0, 0);
        oacc[dn] = __builtin_amdgcn_mfma_f32_16x16x32_bf16(pal[s], vh, oacc[dn], 0, 0, 0);
      }
    }
  }

  float rinv[4];
#pragma unroll
  for (int r = 0; r < 4; r++) rinv[r] = 1.f / rs_[r];
#pragma unroll
  for (int dn = 0; dn < 4; dn++) {
#pragma unroll
    for (int r = 0; r < 4; r++) {
      float v = oacc[dn][r] * rinv[r];
      short hs, ls2;
      split_bf16(v, hs, ls2);
      size_t oidx = (size_t)(tok0 + w * 16 + lh * 4 + r) * E_ + h * 64 + dn * 16 + li;
      t1h[oidx] = hs;
      t1l[oidx] = ls2;
    }
  }
}

// ---------------- cosine similarity ----------------
__global__ __launch_bounds__(256) void cos_kernel(
    const float* __restrict__ a, const float* __restrict__ o,
    float* __restrict__ cosv) {
  int row = blockIdx.x;
  int t = threadIdx.x;
  const float* ar = a + (size_t)row * E_;
  const float* orr = o + (size_t)row * E_;
  float d = 0.f, na = 0.f, nb = 0.f;
#pragma unroll
  for (int j = 0; j < 3; j++) {
    float av = ar[t + 256 * j], ov = orr[t + 256 * j];
    d = fmaf(av, ov, d);
    na = fmaf(av, av, na);
    nb = fmaf(ov, ov, nb);
  }
  d = block_sum256(d);
  na = block_sum256(na);
  nb = block_sum256(nb);
  if (t == 0) cosv[row] = d / fmaxf(sqrtf(na) * sqrtf(nb), 1e-8f);
}

// ---------------- top-k mark (iterative argmax, ties -> lowest index) --------
__device__ void topk_mark(float v, int keep, float* vals, float* bits) {
  int t = threadIdx.x;
  __shared__ float wv[4];
  __shared__ int wi[4];
  vals[t] = v;
  __syncthreads();
  for (int it = 0; it < keep; ++it) {
    float mv = vals[t];
    int mi = t;
#pragma unroll
    for (int off = 32; off; off >>= 1) {
      float ov = __shfl_down(mv, off);
      int oi = __shfl_down(mi, off);
      if (ov > mv || (ov == mv && oi < mi)) { mv = ov; mi = oi; }
    }
    if ((t & 63) == 0) { wv[t >> 6] = mv; wi[t >> 6] = mi; }
    __syncthreads();
    if (t == 0) {
      float bv = wv[0]; int bi = wi[0];
      for (int w = 1; w < 4; ++w)
        if (wv[w] > bv || (wv[w] == bv && wi[w] < bi)) { bv = wv[w]; bi = wi[w]; }
      bits[bi] += 1.f;
      vals[bi] = -INFINITY;
    }
    __syncthreads();
  }
}

// ---------------- final selection ----------------
__global__ __launch_bounds__(256) void select_kernel(
    const float* __restrict__ cosv, const int* __restrict__ typ,
    const float* __restrict__ gh, const float* __restrict__ gt,
    float* __restrict__ out) {
  __shared__ float vals[256];
  __shared__ float bits[256];
  int b = blockIdx.x, t = threadIdx.x;
  int idx = b * 256 + t;
  int ty = typ[idx];
  float c = cosv[idx];
  bits[t] = 0.f;
  float eh = (ty == 1) ? expf(c) : 0.f;
  float sh = block_sum256(eh);
  float glh = (ty == 1) ? (logf(eh / sh) + gh[idx]) : NEGV;
  topk_mark(glh, 64, vals, bits);
  float et = (ty == 2) ? expf(c) : 0.f;
  float st = block_sum256(et);
  float glt = (ty == 2) ? (logf(1.f - et / st) + gt[idx]) : NEGV;
  topk_mark(glt, 63, vals, bits);
  __syncthreads();
  out[idx] = bits[t];
}

// ---------------- host side ----------------
static void launch_gemm(int act, int res, int osplit, const short* Ahi,
                        const short* Alo, const short* Whi, const short* Wlo,
                        const float* bias, const float* R, float* Cf,
                        short* Chi, short* Clo, int M, int N, int K,
                        hipStream_t s) {
  int nx = N / 128, ny = M / 128;
  int nwg = nx * ny;       // 1152 / 1024 / 384 -> all % 8 == 0
  int cpx = nwg / 8;
  dim3 grid(nwg), blk(256);
  if (osplit) {
    gemm_dp<1, 0, 1><<<grid, blk, 0, s>>>(Ahi, Alo, Whi, Wlo, bias, R, Cf, Chi, Clo, M, N, K, nx, cpx);
  } else if (act == 2) {
    gemm_dp<2, 0, 0><<<grid, blk, 0, s>>>(Ahi, Alo, Whi, Wlo, bias, R, Cf, Chi, Clo, M, N, K, nx, cpx);
  } else if (res) {
    gemm_dp<0, 1, 0><<<grid, blk, 0, s>>>(Ahi, Alo, Whi, Wlo, bias, R, Cf, Chi, Clo, M, N, K, nx, cpx);
  } else {
    gemm_dp<0, 0, 0><<<grid, blk, 0, s>>>(Ahi, Alo, Whi, Wlo, bias, R, Cf, Chi, Clo, M, N, K, nx, cpx);
  }
}

extern "C" void kernel_launch(void* const* d_in, const int* in_sizes, int n_in,
                              void* d_out, int out_size, void* d_ws,
                              size_t ws_size, hipStream_t stream) {
  const float* tok = (const float*)d_in[0];
  const int* pos = (const int*)d_in[2];
  const int* typ = (const int*)d_in[3];
  const float* gh = (const float*)d_in[4];
  const float* gt = (const float*)d_in[5];
  const float* pe = (const float*)d_in[6];
  const float* temb = (const float*)d_in[7];
  const float* ln_w = (const float*)d_in[8];
  const float* ln_b = (const float*)d_in[9];
  const float* dense_w = (const float*)d_in[10];
  const float* dense_b = (const float*)d_in[11];
  const float* qkv_w = (const float*)d_in[12];
  const float* qkv_b = (const float*)d_in[13];
  const float* out_w = (const float*)d_in[14];
  const float* out_b = (const float*)d_in[15];
  const float* ln1_w = (const float*)d_in[16];
  const float* ln1_b = (const float*)d_in[17];
  const float* lin1_w = (const float*)d_in[18];
  const float* lin1_b = (const float*)d_in[19];
  const float* lin2_w = (const float*)d_in[20];
  const float* lin2_b = (const float*)d_in[21];
  const float* ln2_w = (const float*)d_in[22];
  const float* ln2_b = (const float*)d_in[23];

  const int M = B_ * S_;
  const size_t NX = (size_t)M * E_;
  const size_t NQKV = (size_t)M * 3 * E_;
  const size_t NFF = (size_t)M * FF_;

  const size_t oQ = 0;
  const size_t oO = oQ + 2 * (size_t)3 * E_ * E_;
  const size_t oL1 = oO + 2 * (size_t)E_ * E_;
  const size_t oL2 = oL1 + 2 * (size_t)FF_ * E_;
  const size_t oD = oL2 + 2 * (size_t)E_ * FF_;
  const size_t WTOT = oD + (size_t)E_ * E_;

  float* ws = (float*)d_ws;
  float* x = ws;
  float* t2 = x + NX;
  float* shared = t2 + NX;
  short* x_hi = (short*)(shared + NQKV);
  short* x_lo = x_hi + NX;
  short* t1_hi = x_lo + NX;
  short* t1_lo = t1_hi + NX;
  short* w_hi = t1_lo + NX;
  short* w_lo = w_hi + WTOT;
  float* cosb = (float*)(w_lo + WTOT);

  short* big_hi = (short*)shared;
  short* big_lo = big_hi + NFF;

  // ---- split weights into bf16 hi/lo planes ----
  {
    int n4;
    n4 = (int)(2 * 3 * E_ * E_ / 4);
    split_kernel<<<(n4 + 255) / 256, 256, 0, stream>>>(qkv_w, w_hi + oQ, w_lo + oQ, n4);
    n4 = (int)(2 * E_ * E_ / 4);
    split_kernel<<<(n4 + 255) / 256, 256, 0, stream>>>(out_w, w_hi + oO, w_lo + oO, n4);
    n4 = (int)(2 * FF_ * E_ / 4);
    split_kernel<<<(n4 + 255) / 256, 256, 0, stream>>>(lin1_w, w_hi + oL1, w_lo + oL1, n4);
    n4 = (int)(2 * E_ * FF_ / 4);
    split_kernel<<<(n4 + 255) / 256, 256, 0, stream>>>(lin2_w, w_hi + oL2, w_lo + oL2, n4);
    n4 = (int)(E_ * E_ / 4);
    split_kernel<<<(n4 + 255) / 256, 256, 0, stream>>>(dense_w, w_hi + oD, w_lo + oD, n4);
  }

  // ---- embed + LN ----
  embed_ln_kernel<<<M, 256, 0, stream>>>(tok, pos, typ, pe, temb, ln_w, ln_b,
                                         x, x_hi, x_lo);

  for (int l = 0; l < L_; l++) {
    const size_t wq = oQ + (size_t)l * 3 * E_ * E_;
    const size_t wo = oO + (size_t)l * E_ * E_;
    const size_t w1 = oL1 + (size_t)l * FF_ * E_;
    const size_t w2 = oL2 + (size_t)l * E_ * FF_;
    // qkv = x @ qkv_w^T + b  -> f32 (shared)
    launch_gemm(0, 0, 0, x_hi, x_lo, w_hi + wq, w_lo + wq,
                qkv_b + (size_t)l * 3 * E_, nullptr, shared, nullptr, nullptr,
                M, 3 * E_, E_, stream);
    // attention -> t1 splits (MFMA)
    attn_kernel<<<dim3(4, H_, B_), 256, 0, stream>>>(shared, t1_hi, t1_lo);
    // t2 = x + t1 @ out_w^T + b
    launch_gemm(0, 1, 0, t1_hi, t1_lo, w_hi + wo, w_lo + wo,
                out_b + (size_t)l * E_, x, t2, nullptr, nullptr, M, E_, E_, stream);
    // x = LN(t2)
    ln_kernel<<<M, 256, 0, stream>>>(t2, ln1_w + (size_t)l * E_,
                                     ln1_b + (size_t)l * E_, x, x_hi, x_lo);
    // big = relu(x @ lin1_w^T + b) -> splits
    launch_gemm(1, 0, 1, x_hi, x_lo, w_hi + w1, w_lo + w1,
                lin1_b + (size_t)l * FF_, nullptr, nullptr, big_hi, big_lo,
                M, FF_, E_, stream);
    // t2 = x + big @ lin2_w^T + b
    launch_gemm(0, 1, 0, big_hi, big_lo, w_hi + w2, w_lo + w2,
                lin2_b + (size_t)l * E_, x, t2, nullptr, nullptr, M, E_, FF_, stream);
    // x = LN(t2)
    ln_kernel<<<M, 256, 0, stream>>>(t2, ln2_w + (size_t)l * E_,
                                     ln2_b + (size_t)l * E_, x, x_hi, x_lo);
  }

  // final LN -> splits into t1 planes
  ln_kernel<<<M, 256, 0, stream>>>(x, ln_w, ln_b, t2, t1_hi, t1_lo);
  // dense: tanh(t1 @ dense_w^T + b) -> f32 (shared region)
  launch_gemm(2, 0, 0, t1_hi, t1_lo, w_hi + oD, w_lo + oD, dense_b, nullptr,
              shared, nullptr, nullptr, M, E_, E_, stream);
  // cos
  cos_kernel<<<M, 256, 0, stream>>>(tok, shared, cosb);
  // selection
  select_kernel<<<B_, 256, 0, stream>>>(cosb, typ, gh, gt, (float*)d_out);
}

// Round 9
// 859.922 us; speedup vs baseline: 1.5412x; 1.0865x over previous
//
#include <hip/hip_runtime.h>
#include <math.h>

#define B_ 32
#define S_ 256
#define E_ 768
#define H_ 12
#define L_ 2
#define FF_ 2048
#define NEGV -1e30f

typedef __attribute__((ext_vector_type(8))) short bf16x8;
typedef __attribute__((ext_vector_type(4))) float f32x4;

// ---------- bf16 split helpers ----------
__device__ __forceinline__ short bf16_rne(float x) {
  unsigned u = __float_as_uint(x);
  u += 0x7fffu + ((u >> 16) & 1u);
  return (short)(u >> 16);
}
__device__ __forceinline__ float bf16_to_f32(short h) {
  return __uint_as_float(((unsigned)(unsigned short)h) << 16);
}
__device__ __forceinline__ void split_bf16(float v, short& h, short& l) {
  h = bf16_rne(v);
  l = bf16_rne(v - bf16_to_f32(h));
}

__device__ __forceinline__ void gl2lds16(const short* g, short* s) {
  __builtin_amdgcn_global_load_lds((const __attribute__((address_space(1))) void*)g,
                                   (__attribute__((address_space(3))) void*)s, 16, 0, 0);
}

// ---------------- block-wide sum over 256 threads ----------------
__device__ __forceinline__ float block_sum256(float v) {
  __shared__ float sh[4];
  int lane = threadIdx.x & 63, w = threadIdx.x >> 6;
#pragma unroll
  for (int off = 32; off; off >>= 1) v += __shfl_down(v, off);
  if (lane == 0) sh[w] = v;
  __syncthreads();
  float tot = sh[0] + sh[1] + sh[2] + sh[3];
  __syncthreads();
  return tot;
}

// ---------------- embed + LN (emits f32 + bf16 split planes) ----------------
__global__ __launch_bounds__(256) void embed_ln_kernel(
    const float* __restrict__ tok, const int* __restrict__ pos,
    const int* __restrict__ typ, const float* __restrict__ pe,
    const float* __restrict__ temb, const float* __restrict__ w,
    const float* __restrict__ b, float* __restrict__ out,
    short* __restrict__ ohi, short* __restrict__ olo) {
  int row = blockIdx.x;
  int t = threadIdx.x;
  int p = pos[row], ty = typ[row];
  const float* tr = tok + (size_t)row * E_;
  const float* pr = pe + (size_t)p * E_;
  const float* yr = temb + (size_t)ty * E_;
  float v0 = tr[t] + pr[t] + yr[t];
  float v1 = tr[t + 256] + pr[t + 256] + yr[t + 256];
  float v2 = tr[t + 512] + pr[t + 512] + yr[t + 512];
  float m = block_sum256(v0 + v1 + v2) * (1.f / E_);
  float d0 = v0 - m, d1 = v1 - m, d2 = v2 - m;
  float var = block_sum256(d0 * d0 + d1 * d1 + d2 * d2) * (1.f / E_);
  float rs = 1.f / sqrtf(var + 1e-5f);
  size_t base = (size_t)row * E_;
  float r0 = d0 * rs * w[t] + b[t];
  float r1 = d1 * rs * w[t + 256] + b[t + 256];
  float r2 = d2 * rs * w[t + 512] + b[t + 512];
  out[base + t] = r0; out[base + t + 256] = r1; out[base + t + 512] = r2;
  short h, l;
  split_bf16(r0, h, l); ohi[base + t] = h; olo[base + t] = l;
  split_bf16(r1, h, l); ohi[base + t + 256] = h; olo[base + t + 256] = l;
  split_bf16(r2, h, l); ohi[base + t + 512] = h; olo[base + t + 512] = l;
}

// ---------------- LN (emits optional f32 + bf16 split planes) ---------------
__global__ __launch_bounds__(256) void ln_kernel(
    const float* __restrict__ in, const float* __restrict__ w,
    const float* __restrict__ b, float* __restrict__ out,
    short* __restrict__ ohi, short* __restrict__ olo) {
  int row = blockIdx.x;
  int t = threadIdx.x;
  const float* p = in + (size_t)row * E_;
  float v0 = p[t], v1 = p[t + 256], v2 = p[t + 512];
  float m = block_sum256(v0 + v1 + v2) * (1.f / E_);
  float d0 = v0 - m, d1 = v1 - m, d2 = v2 - m;
  float var = block_sum256(d0 * d0 + d1 * d1 + d2 * d2) * (1.f / E_);
  float rs = 1.f / sqrtf(var + 1e-5f);
  size_t base = (size_t)row * E_;
  float r0 = d0 * rs * w[t] + b[t];
  float r1 = d1 * rs * w[t + 256] + b[t + 256];
  float r2 = d2 * rs * w[t + 512] + b[t + 512];
  if (out) {
    out[base + t] = r0; out[base + t + 256] = r1; out[base + t + 512] = r2;
  }
  short h, l;
  split_bf16(r0, h, l); ohi[base + t] = h; olo[base + t] = l;
  split_bf16(r1, h, l); ohi[base + t + 256] = h; olo[base + t + 256] = l;
  split_bf16(r2, h, l); ohi[base + t + 512] = h; olo[base + t + 512] = l;
}

// ---------------- weight split: f32 -> (hi, lo) bf16 planes ----------------
__global__ __launch_bounds__(256) void split_kernel(
    const float* __restrict__ src, short* __restrict__ hi,
    short* __restrict__ lo, int n4) {
  int i = blockIdx.x * 256 + threadIdx.x;
  if (i >= n4) return;
  float4 v = ((const float4*)src)[i];
  short4 h, l;
  split_bf16(v.x, h.x, l.x);
  split_bf16(v.y, h.y, l.y);
  split_bf16(v.z, h.z, l.z);
  split_bf16(v.w, h.w, l.w);
  ((short4*)hi)[i] = h;
  ((short4*)lo)[i] = l;
}

// ---------------- deep-pipelined split-bf16 MFMA GEMM (unchanged from R8) ---
template <int ACT, int RES, int OSPLIT>
__global__ __launch_bounds__(256, 2) void gemm_dp(
    const short* __restrict__ Ahi, const short* __restrict__ Alo,
    const short* __restrict__ Whi, const short* __restrict__ Wlo,
    const float* __restrict__ bias, const float* __restrict__ Rres,
    float* __restrict__ Cf, short* __restrict__ Chi, short* __restrict__ Clo,
    int M, int N, int K, int nx, int cpx) {
  __shared__ short lds[2 * 16384];  // dbuf x (4 planes x 4096 shorts)
  const int t = threadIdx.x;
  const int l = t & 63;
  const int w = t >> 6;
  int id = blockIdx.x;
  int id2 = (id & 7) * cpx + (id >> 3);
  const int n0 = (id2 % nx) * 128, m0 = (id2 / nx) * 128;
  const int wm = (w >> 1) * 64, wn = (w & 1) * 64;

  const int g_kb = (l & 3) ^ ((l >> 3) & 3);
  const int r0 = w * 16 + (l >> 2);
  const int r1 = r0 + 64;
  const size_t aof0 = (size_t)(m0 + r0) * K + g_kb * 8;
  const size_t aof1 = (size_t)(m0 + r1) * K + g_kb * 8;
  const size_t wof0 = (size_t)(n0 + r0) * K + g_kb * 8;
  const size_t wof1 = (size_t)(n0 + r1) * K + g_kb * 8;
  const short* pAh0 = Ahi + aof0; const short* pAh1 = Ahi + aof1;
  const short* pAl0 = Alo + aof0; const short* pAl1 = Alo + aof1;
  const short* pWh0 = Whi + wof0; const short* pWh1 = Whi + wof1;
  const short* pWl0 = Wlo + wof0; const short* pWl1 = Wlo + wof1;

  const int kb_r = ((l >> 4) ^ ((l >> 1) & 3)) * 8;
  const short* ra = lds + (wm + (l & 15)) * 32 + kb_r;
  const short* rb = lds + (wn + (l & 15)) * 32 + kb_r;

  f32x4 acc[4][4] = {};
  const int ns = K >> 5;

  auto stage = [&](int buf, int k0) {
    short* base = lds + buf * 16384;
    gl2lds16(pAh0 + k0, base + w * 512);
    gl2lds16(pAh1 + k0, base + (4 + w) * 512);
    gl2lds16(pAl0 + k0, base + 4096 + w * 512);
    gl2lds16(pAl1 + k0, base + 4096 + (4 + w) * 512);
    gl2lds16(pWh0 + k0, base + 8192 + w * 512);
    gl2lds16(pWh1 + k0, base + 8192 + (4 + w) * 512);
    gl2lds16(pWl0 + k0, base + 12288 + w * 512);
    gl2lds16(pWl1 + k0, base + 12288 + (4 + w) * 512);
  };

  stage(0, 0);

  for (int s = 0; s < ns; ++s) {
    const int bp = s & 1;
    __builtin_amdgcn_s_barrier();
    if (s + 1 < ns) {
      stage(bp ^ 1, (s + 1) * 32);
      __builtin_amdgcn_sched_barrier(0);
      asm volatile("s_waitcnt vmcnt(8)" ::: "memory");
    } else {
      __builtin_amdgcn_sched_barrier(0);
      asm volatile("s_waitcnt vmcnt(0)" ::: "memory");
    }
    __builtin_amdgcn_s_barrier();

    const short* rab = ra + bp * 16384;
    const short* rbb = rb + bp * 16384;
    bf16x8 ah[4], al[4], bh[4], bl[4];
#pragma unroll
    for (int i = 0; i < 4; i++) {
      ah[i] = *(const bf16x8*)(rab + i * 512);
      al[i] = *(const bf16x8*)(rab + 4096 + i * 512);
      bh[i] = *(const bf16x8*)(rbb + 8192 + i * 512);
      bl[i] = *(const bf16x8*)(rbb + 12288 + i * 512);
    }
    __builtin_amdgcn_s_setprio(1);
#pragma unroll
    for (int mi = 0; mi < 4; mi++)
#pragma unroll
      for (int ni = 0; ni < 4; ni++) {
        acc[mi][ni] = __builtin_amdgcn_mfma_f32_16x16x32_bf16(ah[mi], bh[ni], acc[mi][ni], 0, 0, 0);
        acc[mi][ni] = __builtin_amdgcn_mfma_f32_16x16x32_bf16(ah[mi], bl[ni], acc[mi][ni], 0, 0, 0);
        acc[mi][ni] = __builtin_amdgcn_mfma_f32_16x16x32_bf16(al[mi], bh[ni], acc[mi][ni], 0, 0, 0);
      }
    __builtin_amdgcn_s_setprio(0);
  }

  const int col_l = l & 15;
  const int row_l = (l >> 4) * 4;
#pragma unroll
  for (int mi = 0; mi < 4; mi++) {
#pragma unroll
    for (int ni = 0; ni < 4; ni++) {
      int col = n0 + wn + ni * 16 + col_l;
      float bv = bias[col];
#pragma unroll
      for (int r = 0; r < 4; r++) {
        int row = m0 + wm + mi * 16 + row_l + r;
        float v = acc[mi][ni][r] + bv;
        if (RES) v += Rres[(size_t)row * N + col];
        if (ACT == 1) v = fmaxf(v, 0.f);
        if (ACT == 2) v = tanhf(v);
        if (OSPLIT) {
          short h2, l2;
          split_bf16(v, h2, l2);
          Chi[(size_t)row * N + col] = h2;
          Clo[(size_t)row * N + col] = l2;
        } else {
          Cf[(size_t)row * N + col] = v;
        }
      }
    }
  }
}

// ---------------- MFMA split-bf16 attention (unchanged from R6) ----------
__global__ __launch_bounds__(256, 2) void attn_kernel(
    const float* __restrict__ qkv, short* __restrict__ t1h,
    short* __restrict__ t1l) {
  __shared__ short lds[16384];
  const int qt = blockIdx.x, h = blockIdx.y, b = blockIdx.z;
  const int t = threadIdx.x;
  const int w = t >> 6, l = t & 63;
  const int li = l & 15, lh = l >> 4;

  short* kh = lds;
  short* kl = lds + 4096;
  short* ph = lds + 8192 + w * 2048;
  short* pl = ph + 1024;

  const int tok0 = b * S_ + qt * 64;

  bf16x8 qh[2], ql[2];
  {
    const float* qrow = qkv + (size_t)(tok0 + w * 16 + li) * 2304 + h * 64 + lh * 8;
#pragma unroll
    for (int s = 0; s < 2; s++) {
      float4 f0 = *(const float4*)(qrow + s * 32);
      float4 f1 = *(const float4*)(qrow + s * 32 + 4);
      float f[8] = {f0.x, f0.y, f0.z, f0.w, f1.x, f1.y, f1.z, f1.w};
      bf16x8 hv, lv;
#pragma unroll
      for (int j = 0; j < 8; j++) {
        short hs, ls2;
        split_bf16(f[j], hs, ls2);
        hv[j] = hs; lv[j] = ls2;
      }
      qh[s] = hv; ql[s] = lv;
    }
  }

  const int skk = t >> 2, sd0 = (t & 3) * 16;

  f32x4 acc[16] = {};

  const float* kbase = qkv + (size_t)(b * S_) * 2304 + 768 + h * 64;
#pragma unroll
  for (int c = 0; c < 4; c++) {
    __syncthreads();
    {
      const float* src = kbase + (size_t)(c * 64 + skk) * 2304 + sd0;
#pragma unroll
      for (int i = 0; i < 4; i++) {
        float4 f = *(const float4*)(src + i * 4);
        int d = sd0 + i * 4;
        short4 hv, lv;
        split_bf16(f.x, hv.x, lv.x);
        split_bf16(f.y, hv.y, lv.y);
        split_bf16(f.z, hv.z, lv.z);
        split_bf16(f.w, hv.w, lv.w);
        int off = skk * 64 + ((((d >> 3) ^ (skk & 7)) & 7) << 3) + (d & 7);
        *(short4*)(kh + off) = hv;
        *(short4*)(kl + off) = lv;
      }
    }
    __syncthreads();
#pragma unroll
    for (int nn = 0; nn < 4; nn++) {
      const int krow = nn * 16 + li;
#pragma unroll
      for (int s = 0; s < 2; s++) {
        const int off = krow * 64 + ((((s * 4 + lh) ^ (li & 7)) & 7) << 3);
        bf16x8 bh = *(const bf16x8*)(kh + off);
        bf16x8 bl = *(const bf16x8*)(kl + off);
        acc[c * 4 + nn] = __builtin_amdgcn_mfma_f32_16x16x32_bf16(qh[s], bh, acc[c * 4 + nn], 0, 0, 0);
        acc[c * 4 + nn] = __builtin_amdgcn_mfma_f32_16x16x32_bf16(qh[s], bl, acc[c * 4 + nn], 0, 0, 0);
        acc[c * 4 + nn] = __builtin_amdgcn_mfma_f32_16x16x32_bf16(ql[s], bh, acc[c * 4 + nn], 0, 0, 0);
      }
    }
  }

  float rs_[4];
#pragma unroll
  for (int r = 0; r < 4; r++) {
    float m = -3.4e38f;
#pragma unroll
    for (int fi = 0; fi < 16; fi++) m = fmaxf(m, acc[fi][r]);
#pragma unroll
    for (int off = 8; off; off >>= 1) m = fmaxf(m, __shfl_xor(m, off));
    float sum = 0.f;
#pragma unroll
    for (int fi = 0; fi < 16; fi++) {
      float p = expf((acc[fi][r] - m) * 0.125f);
      acc[fi][r] = p;
      sum += p;
    }
#pragma unroll
    for (int off = 8; off; off >>= 1) sum += __shfl_xor(sum, off);
    rs_[r] = sum;
  }

  f32x4 oacc[4] = {};
  const float* vbase = qkv + (size_t)(b * S_) * 2304 + 1536 + h * 64;
#pragma unroll
  for (int c = 0; c < 4; c++) {
    __syncthreads();
    {
      const float* src = vbase + (size_t)(c * 64 + skk) * 2304 + sd0;
#pragma unroll
      for (int i = 0; i < 4; i++) {
        float4 f = *(const float4*)(src + i * 4);
        float fv[4] = {f.x, f.y, f.z, f.w};
#pragma unroll
        for (int j = 0; j < 4; j++) {
          int d = sd0 + i * 4 + j;
          short hs, ls2;
          split_bf16(fv[j], hs, ls2);
          int sw = (d & 7) ^ ((d >> 3) & 7);
          int off = d * 64 + ((((skk >> 3) ^ sw) & 7) << 3) + (skk & 7);
          kh[off] = hs;
          kl[off] = ls2;
        }
      }
    }
#pragma unroll
    for (int nn = 0; nn < 4; nn++) {
#pragma unroll
      for (int r = 0; r < 4; r++) {
        const int q = lh * 4 + r;
        const int keyl = li + 16 * nn;
        short hs, ls2;
        split_bf16(acc[c * 4 + nn][r], hs, ls2);
        const int off = q * 64 + ((((keyl >> 3) ^ (q & 7)) & 7) << 3) + (keyl & 7);
        ph[off] = hs;
        pl[off] = ls2;
      }
    }
    __syncthreads();
    bf16x8 pah[2], pal[2];
#pragma unroll
    for (int s = 0; s < 2; s++) {
      const int off = li * 64 + ((((s * 4 + lh) ^ (li & 7)) & 7) << 3);
      pah[s] = *(const bf16x8*)(ph + off);
      pal[s] = *(const bf16x8*)(pl + off);
    }
#pragma unroll
    for (int dn = 0; dn < 4; dn++) {
      const int drow = dn * 16 + li;
      const int sw = ((drow & 7) ^ ((drow >> 3) & 7)) & 7;
#pragma unroll
      for (int s = 0; s < 2; s++) {
        const int off = drow * 64 + ((((s * 4 + lh) ^ sw) & 7) << 3);
        bf16x8 vh = *(const bf16x8*)(kh + off);
        bf16x8 vl = *(const bf16x8*)(kl + off);
        oacc[dn] = __builtin_amdgcn_mfma_f32_16x16x32_bf16(pah[s], vh, oacc[dn], 0, 0, 0);
        oacc[dn] = __builtin_amdgcn_mfma_f32_16x16x32_bf16(pah[s], vl, oacc[dn], 0, 0, 0);
        oacc[dn] = __builtin_amdgcn_mfma_f32_16x16x32_bf16(pal[s], vh, oacc[dn], 0, 0, 0);
      }
    }
  }

  float rinv[4];
#pragma unroll
  for (int r = 0; r < 4; r++) rinv[r] = 1.f / rs_[r];
#pragma unroll
  for (int dn = 0; dn < 4; dn++) {
#pragma unroll
    for (int r = 0; r < 4; r++) {
      float v = oacc[dn][r] * rinv[r];
      short hs, ls2;
      split_bf16(v, hs, ls2);
      size_t oidx = (size_t)(tok0 + w * 16 + lh * 4 + r) * E_ + h * 64 + dn * 16 + li;
      t1h[oidx] = hs;
      t1l[oidx] = ls2;
    }
  }
}

// ---------------- cosine similarity ----------------
__global__ __launch_bounds__(256) void cos_kernel(
    const float* __restrict__ a, const float* __restrict__ o,
    float* __restrict__ cosv) {
  int row = blockIdx.x;
  int t = threadIdx.x;
  const float* ar = a + (size_t)row * E_;
  const float* orr = o + (size_t)row * E_;
  float d = 0.f, na = 0.f, nb = 0.f;
#pragma unroll
  for (int j = 0; j < 3; j++) {
    float av = ar[t + 256 * j], ov = orr[t + 256 * j];
    d = fmaf(av, ov, d);
    na = fmaf(av, av, na);
    nb = fmaf(ov, ov, nb);
  }
  d = block_sum256(d);
  na = block_sum256(na);
  nb = block_sum256(nb);
  if (t == 0) cosv[row] = d / fmaxf(sqrtf(na) * sqrtf(nb), 1e-8f);
}

// ---------------- final selection: rank-based parallel top-k ----------------
// Element i is selected iff #{j : v_j > v_i or (v_j == v_i and j < i)} < keep
// -- identical set and tie semantics to iterative argmax (ties -> lowest
// index), but all 256 ranks computed in parallel (no serial loop).
__global__ __launch_bounds__(256) void select_kernel(
    const float* __restrict__ cosv, const int* __restrict__ typ,
    const float* __restrict__ gh, const float* __restrict__ gt,
    float* __restrict__ out) {
  __shared__ float vals[256];
  int b = blockIdx.x, t = threadIdx.x;
  int idx = b * 256 + t;
  int ty = typ[idx];
  float c = cosv[idx];
  float res = 0.f;

  // ---- hist: masked softmax over type==1, keep top-64 of gl ----
  float eh = (ty == 1) ? expf(c) : 0.f;
  float sh = block_sum256(eh);
  float glh = (ty == 1) ? (logf(eh / sh) + gh[idx]) : NEGV;
  vals[t] = glh;
  __syncthreads();
  {
    int rank = 0;
#pragma unroll
    for (int j = 0; j < 64; ++j) {
      float4 q = *(const float4*)&vals[j * 4];
      rank += (q.x > glh) || (q.x == glh && (j * 4 + 0) < t);
      rank += (q.y > glh) || (q.y == glh && (j * 4 + 1) < t);
      rank += (q.z > glh) || (q.z == glh && (j * 4 + 2) < t);
      rank += (q.w > glh) || (q.w == glh && (j * 4 + 3) < t);
    }
    if (ty == 1 && rank < 64) res += 1.f;  // KEEP_HIST = 64
  }
  __syncthreads();

  // ---- tgt: 1 - masked softmax over type==2, keep top-63 of gl ----
  float et = (ty == 2) ? expf(c) : 0.f;
  float st = block_sum256(et);
  float glt = (ty == 2) ? (logf(1.f - et / st) + gt[idx]) : NEGV;
  vals[t] = glt;
  __syncthreads();
  {
    int rank = 0;
#pragma unroll
    for (int j = 0; j < 64; ++j) {
      float4 q = *(const float4*)&vals[j * 4];
      rank += (q.x > glt) || (q.x == glt && (j * 4 + 0) < t);
      rank += (q.y > glt) || (q.y == glt && (j * 4 + 1) < t);
      rank += (q.z > glt) || (q.z == glt && (j * 4 + 2) < t);
      rank += (q.w > glt) || (q.w == glt && (j * 4 + 3) < t);
    }
    if (ty == 2 && rank < 63) res += 1.f;  // KEEP_TGT = 63
  }
  out[idx] = res;
}

// ---------------- host side ----------------
static void launch_gemm(int act, int res, int osplit, const short* Ahi,
                        const short* Alo, const short* Whi, const short* Wlo,
                        const float* bias, const float* R, float* Cf,
                        short* Chi, short* Clo, int M, int N, int K,
                        hipStream_t s) {
  int nx = N / 128, ny = M / 128;
  int nwg = nx * ny;
  int cpx = nwg / 8;
  dim3 grid(nwg), blk(256);
  if (osplit) {
    gemm_dp<1, 0, 1><<<grid, blk, 0, s>>>(Ahi, Alo, Whi, Wlo, bias, R, Cf, Chi, Clo, M, N, K, nx, cpx);
  } else if (act == 2) {
    gemm_dp<2, 0, 0><<<grid, blk, 0, s>>>(Ahi, Alo, Whi, Wlo, bias, R, Cf, Chi, Clo, M, N, K, nx, cpx);
  } else if (res) {
    gemm_dp<0, 1, 0><<<grid, blk, 0, s>>>(Ahi, Alo, Whi, Wlo, bias, R, Cf, Chi, Clo, M, N, K, nx, cpx);
  } else {
    gemm_dp<0, 0, 0><<<grid, blk, 0, s>>>(Ahi, Alo, Whi, Wlo, bias, R, Cf, Chi, Clo, M, N, K, nx, cpx);
  }
}

extern "C" void kernel_launch(void* const* d_in, const int* in_sizes, int n_in,
                              void* d_out, int out_size, void* d_ws,
                              size_t ws_size, hipStream_t stream) {
  const float* tok = (const float*)d_in[0];
  const int* pos = (const int*)d_in[2];
  const int* typ = (const int*)d_in[3];
  const float* gh = (const float*)d_in[4];
  const float* gt = (const float*)d_in[5];
  const float* pe = (const float*)d_in[6];
  const float* temb = (const float*)d_in[7];
  const float* ln_w = (const float*)d_in[8];
  const float* ln_b = (const float*)d_in[9];
  const float* dense_w = (const float*)d_in[10];
  const float* dense_b = (const float*)d_in[11];
  const float* qkv_w = (const float*)d_in[12];
  const float* qkv_b = (const float*)d_in[13];
  const float* out_w = (const float*)d_in[14];
  const float* out_b = (const float*)d_in[15];
  const float* ln1_w = (const float*)d_in[16];
  const float* ln1_b = (const float*)d_in[17];
  const float* lin1_w = (const float*)d_in[18];
  const float* lin1_b = (const float*)d_in[19];
  const float* lin2_w = (const float*)d_in[20];
  const float* lin2_b = (const float*)d_in[21];
  const float* ln2_w = (const float*)d_in[22];
  const float* ln2_b = (const float*)d_in[23];

  const int M = B_ * S_;
  const size_t NX = (size_t)M * E_;
  const size_t NQKV = (size_t)M * 3 * E_;
  const size_t NFF = (size_t)M * FF_;

  const size_t oQ = 0;
  const size_t oO = oQ + 2 * (size_t)3 * E_ * E_;
  const size_t oL1 = oO + 2 * (size_t)E_ * E_;
  const size_t oL2 = oL1 + 2 * (size_t)FF_ * E_;
  const size_t oD = oL2 + 2 * (size_t)E_ * FF_;
  const size_t WTOT = oD + (size_t)E_ * E_;

  float* ws = (float*)d_ws;
  float* x = ws;
  float* t2 = x + NX;
  float* shared = t2 + NX;
  short* x_hi = (short*)(shared + NQKV);
  short* x_lo = x_hi + NX;
  short* t1_hi = x_lo + NX;
  short* t1_lo = t1_hi + NX;
  short* w_hi = t1_lo + NX;
  short* w_lo = w_hi + WTOT;
  float* cosb = (float*)(w_lo + WTOT);

  short* big_hi = (short*)shared;
  short* big_lo = big_hi + NFF;

  // ---- split weights into bf16 hi/lo planes ----
  {
    int n4;
    n4 = (int)(2 * 3 * E_ * E_ / 4);
    split_kernel<<<(n4 + 255) / 256, 256, 0, stream>>>(qkv_w, w_hi + oQ, w_lo + oQ, n4);
    n4 = (int)(2 * E_ * E_ / 4);
    split_kernel<<<(n4 + 255) / 256, 256, 0, stream>>>(out_w, w_hi + oO, w_lo + oO, n4);
    n4 = (int)(2 * FF_ * E_ / 4);
    split_kernel<<<(n4 + 255) / 256, 256, 0, stream>>>(lin1_w, w_hi + oL1, w_lo + oL1, n4);
    n4 = (int)(2 * E_ * FF_ / 4);
    split_kernel<<<(n4 + 255) / 256, 256, 0, stream>>>(lin2_w, w_hi + oL2, w_lo + oL2, n4);
    n4 = (int)(E_ * E_ / 4);
    split_kernel<<<(n4 + 255) / 256, 256, 0, stream>>>(dense_w, w_hi + oD, w_lo + oD, n4);
  }

  // ---- embed + LN ----
  embed_ln_kernel<<<M, 256, 0, stream>>>(tok, pos, typ, pe, temb, ln_w, ln_b,
                                         x, x_hi, x_lo);

  for (int l = 0; l < L_; l++) {
    const size_t wq = oQ + (size_t)l * 3 * E_ * E_;
    const size_t wo = oO + (size_t)l * E_ * E_;
    const size_t w1 = oL1 + (size_t)l * FF_ * E_;
    const size_t w2 = oL2 + (size_t)l * E_ * FF_;
    // qkv = x @ qkv_w^T + b  -> f32 (shared)
    launch_gemm(0, 0, 0, x_hi, x_lo, w_hi + wq, w_lo + wq,
                qkv_b + (size_t)l * 3 * E_, nullptr, shared, nullptr, nullptr,
                M, 3 * E_, E_, stream);
    // attention -> t1 splits (MFMA)
    attn_kernel<<<dim3(4, H_, B_), 256, 0, stream>>>(shared, t1_hi, t1_lo);
    // t2 = x + t1 @ out_w^T + b
    launch_gemm(0, 1, 0, t1_hi, t1_lo, w_hi + wo, w_lo + wo,
                out_b + (size_t)l * E_, x, t2, nullptr, nullptr, M, E_, E_, stream);
    // x = LN(t2)
    ln_kernel<<<M, 256, 0, stream>>>(t2, ln1_w + (size_t)l * E_,
                                     ln1_b + (size_t)l * E_, x, x_hi, x_lo);
    // big = relu(x @ lin1_w^T + b) -> splits
    launch_gemm(1, 0, 1, x_hi, x_lo, w_hi + w1, w_lo + w1,
                lin1_b + (size_t)l * FF_, nullptr, nullptr, big_hi, big_lo,
                M, FF_, E_, stream);
    // t2 = x + big @ lin2_w^T + b
    launch_gemm(0, 1, 0, big_hi, big_lo, w_hi + w2, w_lo + w2,
                lin2_b + (size_t)l * E_, x, t2, nullptr, nullptr, M, E_, FF_, stream);
    // x = LN(t2)
    ln_kernel<<<M, 256, 0, stream>>>(t2, ln2_w + (size_t)l * E_,
                                     ln2_b + (size_t)l * E_, x, x_hi, x_lo);
  }

  // final LN -> splits only (f32 output dead; skip the write)
  ln_kernel<<<M, 256, 0, stream>>>(x, ln_w, ln_b, nullptr, t1_hi, t1_lo);
  // dense: tanh(t1 @ dense_w^T + b) -> f32 (shared region)
  launch_gemm(2, 0, 0, t1_hi, t1_lo, w_hi + oD, w_lo + oD, dense_b, nullptr,
              shared, nullptr, nullptr, M, E_, E_, stream);
  // cos
  cos_kernel<<<M, 256, 0, stream>>>(tok, shared, cosb);
  // selection
  select_kernel<<<B_, 256, 0, stream>>>(cosb, typ, gh, gt, (float*)d_out);
}

// Round 10
// 836.694 us; speedup vs baseline: 1.5840x; 1.0278x over previous
//
#include <hip/hip_runtime.h>
#include <math.h>

#define B_ 32
#define S_ 256
#define E_ 768
#define H_ 12
#define L_ 2
#define FF_ 2048
#define NEGV -1e30f

typedef __attribute__((ext_vector_type(8))) short bf16x8;
typedef __attribute__((ext_vector_type(4))) float f32x4;

// ---------- bf16 split helpers ----------
__device__ __forceinline__ short bf16_rne(float x) {
  unsigned u = __float_as_uint(x);
  u += 0x7fffu + ((u >> 16) & 1u);
  return (short)(u >> 16);
}
__device__ __forceinline__ float bf16_to_f32(short h) {
  return __uint_as_float(((unsigned)(unsigned short)h) << 16);
}
__device__ __forceinline__ void split_bf16(float v, short& h, short& l) {
  h = bf16_rne(v);
  l = bf16_rne(v - bf16_to_f32(h));
}

__device__ __forceinline__ void gl2lds16(const short* g, short* s) {
  __builtin_amdgcn_global_load_lds((const __attribute__((address_space(1))) void*)g,
                                   (__attribute__((address_space(3))) void*)s, 16, 0, 0);
}

// ---------------- block-wide sum over 256 threads ----------------
__device__ __forceinline__ float block_sum256(float v) {
  __shared__ float sh[4];
  int lane = threadIdx.x & 63, w = threadIdx.x >> 6;
#pragma unroll
  for (int off = 32; off; off >>= 1) v += __shfl_down(v, off);
  if (lane == 0) sh[w] = v;
  __syncthreads();
  float tot = sh[0] + sh[1] + sh[2] + sh[3];
  __syncthreads();
  return tot;
}

// ---------------- embed + LN (emits f32 + bf16 split planes) ----------------
__global__ __launch_bounds__(256) void embed_ln_kernel(
    const float* __restrict__ tok, const int* __restrict__ pos,
    const int* __restrict__ typ, const float* __restrict__ pe,
    const float* __restrict__ temb, const float* __restrict__ w,
    const float* __restrict__ b, float* __restrict__ out,
    short* __restrict__ ohi, short* __restrict__ olo) {
  int row = blockIdx.x;
  int t = threadIdx.x;
  int p = pos[row], ty = typ[row];
  const float* tr = tok + (size_t)row * E_;
  const float* pr = pe + (size_t)p * E_;
  const float* yr = temb + (size_t)ty * E_;
  float v0 = tr[t] + pr[t] + yr[t];
  float v1 = tr[t + 256] + pr[t + 256] + yr[t + 256];
  float v2 = tr[t + 512] + pr[t + 512] + yr[t + 512];
  float m = block_sum256(v0 + v1 + v2) * (1.f / E_);
  float d0 = v0 - m, d1 = v1 - m, d2 = v2 - m;
  float var = block_sum256(d0 * d0 + d1 * d1 + d2 * d2) * (1.f / E_);
  float rs = 1.f / sqrtf(var + 1e-5f);
  size_t base = (size_t)row * E_;
  float r0 = d0 * rs * w[t] + b[t];
  float r1 = d1 * rs * w[t + 256] + b[t + 256];
  float r2 = d2 * rs * w[t + 512] + b[t + 512];
  out[base + t] = r0; out[base + t + 256] = r1; out[base + t + 512] = r2;
  short h, l;
  split_bf16(r0, h, l); ohi[base + t] = h; olo[base + t] = l;
  split_bf16(r1, h, l); ohi[base + t + 256] = h; olo[base + t + 256] = l;
  split_bf16(r2, h, l); ohi[base + t + 512] = h; olo[base + t + 512] = l;
}

// ---------------- LN (emits optional f32 + bf16 split planes) ---------------
__global__ __launch_bounds__(256) void ln_kernel(
    const float* __restrict__ in, const float* __restrict__ w,
    const float* __restrict__ b, float* __restrict__ out,
    short* __restrict__ ohi, short* __restrict__ olo) {
  int row = blockIdx.x;
  int t = threadIdx.x;
  const float* p = in + (size_t)row * E_;
  float v0 = p[t], v1 = p[t + 256], v2 = p[t + 512];
  float m = block_sum256(v0 + v1 + v2) * (1.f / E_);
  float d0 = v0 - m, d1 = v1 - m, d2 = v2 - m;
  float var = block_sum256(d0 * d0 + d1 * d1 + d2 * d2) * (1.f / E_);
  float rs = 1.f / sqrtf(var + 1e-5f);
  size_t base = (size_t)row * E_;
  float r0 = d0 * rs * w[t] + b[t];
  float r1 = d1 * rs * w[t + 256] + b[t + 256];
  float r2 = d2 * rs * w[t + 512] + b[t + 512];
  if (out) {
    out[base + t] = r0; out[base + t + 256] = r1; out[base + t + 512] = r2;
  }
  short h, l;
  split_bf16(r0, h, l); ohi[base + t] = h; olo[base + t] = l;
  split_bf16(r1, h, l); ohi[base + t + 256] = h; olo[base + t + 256] = l;
  split_bf16(r2, h, l); ohi[base + t + 512] = h; olo[base + t + 512] = l;
}

// ---------------- weight split: f32 -> (hi, lo) bf16 planes ----------------
__global__ __launch_bounds__(256) void split_kernel(
    const float* __restrict__ src, short* __restrict__ hi,
    short* __restrict__ lo, int n4) {
  int i = blockIdx.x * 256 + threadIdx.x;
  if (i >= n4) return;
  float4 v = ((const float4*)src)[i];
  short4 h, l;
  split_bf16(v.x, h.x, l.x);
  split_bf16(v.y, h.y, l.y);
  split_bf16(v.z, h.z, l.z);
  split_bf16(v.w, h.w, l.w);
  ((short4*)hi)[i] = h;
  ((short4*)lo)[i] = l;
}

// ---------------- deep-pipelined split-bf16 MFMA GEMM, 128x128 tile ---------
// (R8 structure; used for lin1 where N=2048 is not 192-divisible)
template <int ACT, int RES, int OSPLIT>
__global__ __launch_bounds__(256, 2) void gemm_dp(
    const short* __restrict__ Ahi, const short* __restrict__ Alo,
    const short* __restrict__ Whi, const short* __restrict__ Wlo,
    const float* __restrict__ bias, const float* __restrict__ Rres,
    float* __restrict__ Cf, short* __restrict__ Chi, short* __restrict__ Clo,
    int M, int N, int K, int nx, int cpx) {
  __shared__ short lds[2 * 16384];
  const int t = threadIdx.x;
  const int l = t & 63;
  const int w = t >> 6;
  int id = blockIdx.x;
  int id2 = (id & 7) * cpx + (id >> 3);
  const int n0 = (id2 % nx) * 128, m0 = (id2 / nx) * 128;
  const int wm = (w >> 1) * 64, wn = (w & 1) * 64;

  const int g_kb = (l & 3) ^ ((l >> 3) & 3);
  const int r0 = w * 16 + (l >> 2);
  const int r1 = r0 + 64;
  const size_t aof0 = (size_t)(m0 + r0) * K + g_kb * 8;
  const size_t aof1 = (size_t)(m0 + r1) * K + g_kb * 8;
  const size_t wof0 = (size_t)(n0 + r0) * K + g_kb * 8;
  const size_t wof1 = (size_t)(n0 + r1) * K + g_kb * 8;
  const short* pAh0 = Ahi + aof0; const short* pAh1 = Ahi + aof1;
  const short* pAl0 = Alo + aof0; const short* pAl1 = Alo + aof1;
  const short* pWh0 = Whi + wof0; const short* pWh1 = Whi + wof1;
  const short* pWl0 = Wlo + wof0; const short* pWl1 = Wlo + wof1;

  const int kb_r = ((l >> 4) ^ ((l >> 1) & 3)) * 8;
  const short* ra = lds + (wm + (l & 15)) * 32 + kb_r;
  const short* rb = lds + (wn + (l & 15)) * 32 + kb_r;

  f32x4 acc[4][4] = {};
  const int ns = K >> 5;

  auto stage = [&](int buf, int k0) {
    short* base = lds + buf * 16384;
    gl2lds16(pAh0 + k0, base + w * 512);
    gl2lds16(pAh1 + k0, base + (4 + w) * 512);
    gl2lds16(pAl0 + k0, base + 4096 + w * 512);
    gl2lds16(pAl1 + k0, base + 4096 + (4 + w) * 512);
    gl2lds16(pWh0 + k0, base + 8192 + w * 512);
    gl2lds16(pWh1 + k0, base + 8192 + (4 + w) * 512);
    gl2lds16(pWl0 + k0, base + 12288 + w * 512);
    gl2lds16(pWl1 + k0, base + 12288 + (4 + w) * 512);
  };

  stage(0, 0);

  for (int s = 0; s < ns; ++s) {
    const int bp = s & 1;
    __builtin_amdgcn_s_barrier();
    if (s + 1 < ns) {
      stage(bp ^ 1, (s + 1) * 32);
      __builtin_amdgcn_sched_barrier(0);
      asm volatile("s_waitcnt vmcnt(8)" ::: "memory");
    } else {
      __builtin_amdgcn_sched_barrier(0);
      asm volatile("s_waitcnt vmcnt(0)" ::: "memory");
    }
    __builtin_amdgcn_s_barrier();

    const short* rab = ra + bp * 16384;
    const short* rbb = rb + bp * 16384;
    bf16x8 ah[4], al[4], bh[4], bl[4];
#pragma unroll
    for (int i = 0; i < 4; i++) {
      ah[i] = *(const bf16x8*)(rab + i * 512);
      al[i] = *(const bf16x8*)(rab + 4096 + i * 512);
      bh[i] = *(const bf16x8*)(rbb + 8192 + i * 512);
      bl[i] = *(const bf16x8*)(rbb + 12288 + i * 512);
    }
    __builtin_amdgcn_s_setprio(1);
#pragma unroll
    for (int mi = 0; mi < 4; mi++)
#pragma unroll
      for (int ni = 0; ni < 4; ni++) {
        acc[mi][ni] = __builtin_amdgcn_mfma_f32_16x16x32_bf16(ah[mi], bh[ni], acc[mi][ni], 0, 0, 0);
        acc[mi][ni] = __builtin_amdgcn_mfma_f32_16x16x32_bf16(ah[mi], bl[ni], acc[mi][ni], 0, 0, 0);
        acc[mi][ni] = __builtin_amdgcn_mfma_f32_16x16x32_bf16(al[mi], bh[ni], acc[mi][ni], 0, 0, 0);
      }
    __builtin_amdgcn_s_setprio(0);
  }

  const int col_l = l & 15;
  const int row_l = (l >> 4) * 4;
#pragma unroll
  for (int mi = 0; mi < 4; mi++) {
#pragma unroll
    for (int ni = 0; ni < 4; ni++) {
      int col = n0 + wn + ni * 16 + col_l;
      float bv = bias[col];
#pragma unroll
      for (int r = 0; r < 4; r++) {
        int row = m0 + wm + mi * 16 + row_l + r;
        float v = acc[mi][ni][r] + bv;
        if (RES) v += Rres[(size_t)row * N + col];
        if (ACT == 1) v = fmaxf(v, 0.f);
        if (ACT == 2) v = tanhf(v);
        if (OSPLIT) {
          short h2, l2;
          split_bf16(v, h2, l2);
          Chi[(size_t)row * N + col] = h2;
          Clo[(size_t)row * N + col] = l2;
        } else {
          Cf[(size_t)row * N + col] = v;
        }
      }
    }
  }
}

// ---------------- split-bf16 MFMA GEMM, 128x192 tile (wave 64x96) -----------
// Same counted-vmcnt dbuf schedule; wider wave tile raises FLOP/LDS-byte by
// 20% (reads 20 KB per 1.18 MFLOP, MFMA:ds_read = 72:20).  LDS = 2 x 40 KB
// = 80 KB -> exactly 2 blocks/CU.  Requires N % 192 == 0.
template <int ACT, int RES>
__global__ __launch_bounds__(256, 2) void gemm_dp2(
    const short* __restrict__ Ahi, const short* __restrict__ Alo,
    const short* __restrict__ Whi, const short* __restrict__ Wlo,
    const float* __restrict__ bias, const float* __restrict__ Rres,
    float* __restrict__ Cf, int M, int N, int K, int nx, int cpx) {
  __shared__ short lds[2 * 20480];  // dbuf x (A 2x4096 | W 2x6144 shorts)
  const int t = threadIdx.x;
  const int l = t & 63;
  const int w = t >> 6;
  int id = blockIdx.x;
  int id2 = (id & 7) * cpx + (id >> 3);
  const int n0 = (id2 % nx) * 192, m0 = (id2 / nx) * 128;
  const int wm = (w >> 1) * 64;   // wave row offset (2 m-waves)
  const int wn = (w & 1) * 96;    // wave col offset (2 n-waves)

  // staging: op j covers rows j*64 + w*16 + (l>>2); source kb XOR-swizzled
  const int g_kb = (l & 3) ^ ((l >> 3) & 3);
  const int srow = w * 16 + (l >> 2);
  const size_t a0 = (size_t)(m0 + srow) * K + g_kb * 8;
  const size_t a1 = (size_t)(m0 + 64 + srow) * K + g_kb * 8;
  const size_t w0 = (size_t)(n0 + srow) * K + g_kb * 8;
  const size_t w1 = (size_t)(n0 + 64 + srow) * K + g_kb * 8;
  const size_t w2 = (size_t)(n0 + 128 + srow) * K + g_kb * 8;
  const short* pAh0 = Ahi + a0; const short* pAh1 = Ahi + a1;
  const short* pAl0 = Alo + a0; const short* pAl1 = Alo + a1;
  const short* pWh0 = Whi + w0; const short* pWh1 = Whi + w1; const short* pWh2 = Whi + w2;
  const short* pWl0 = Wlo + w0; const short* pWl1 = Wlo + w1; const short* pWl2 = Wlo + w2;

  // frag reads: row*32 + (kb ^ ((row>>1)&3))*8 ; lane-constant XOR
  const int kb_r = ((l >> 4) ^ ((l >> 1) & 3)) * 8;
  const short* ra = lds + (wm + (l & 15)) * 32 + kb_r;          // A planes
  const short* rb = lds + 8192 + (wn + (l & 15)) * 32 + kb_r;   // W planes

  f32x4 acc[4][6] = {};
  const int ns = K >> 5;

  auto stage = [&](int buf, int k0) {
    short* base = lds + buf * 20480;
    gl2lds16(pAh0 + k0, base + w * 512);
    gl2lds16(pAh1 + k0, base + 2048 + w * 512);
    gl2lds16(pAl0 + k0, base + 4096 + w * 512);
    gl2lds16(pAl1 + k0, base + 4096 + 2048 + w * 512);
    gl2lds16(pWh0 + k0, base + 8192 + w * 512);
    gl2lds16(pWh1 + k0, base + 8192 + 2048 + w * 512);
    gl2lds16(pWh2 + k0, base + 8192 + 4096 + w * 512);
    gl2lds16(pWl0 + k0, base + 14336 + w * 512);
    gl2lds16(pWl1 + k0, base + 14336 + 2048 + w * 512);
    gl2lds16(pWl2 + k0, base + 14336 + 4096 + w * 512);
  };

  stage(0, 0);

  for (int s = 0; s < ns; ++s) {
    const int bp = s & 1;
    __builtin_amdgcn_s_barrier();
    if (s + 1 < ns) {
      stage(bp ^ 1, (s + 1) * 32);
      __builtin_amdgcn_sched_barrier(0);
      asm volatile("s_waitcnt vmcnt(10)" ::: "memory");
    } else {
      __builtin_amdgcn_sched_barrier(0);
      asm volatile("s_waitcnt vmcnt(0)" ::: "memory");
    }
    __builtin_amdgcn_s_barrier();

    const short* rab = ra + bp * 20480;
    const short* rbb = rb + bp * 20480;
    bf16x8 bh[6], bl[6];
#pragma unroll
    for (int i = 0; i < 6; i++) {
      bh[i] = *(const bf16x8*)(rbb + i * 512);
      bl[i] = *(const bf16x8*)(rbb + 6144 + i * 512);
    }
    __builtin_amdgcn_s_setprio(1);
#pragma unroll
    for (int mi = 0; mi < 4; mi++) {
      bf16x8 ah = *(const bf16x8*)(rab + mi * 512);
      bf16x8 al = *(const bf16x8*)(rab + 4096 + mi * 512);
#pragma unroll
      for (int ni = 0; ni < 6; ni++) {
        acc[mi][ni] = __builtin_amdgcn_mfma_f32_16x16x32_bf16(ah, bh[ni], acc[mi][ni], 0, 0, 0);
        acc[mi][ni] = __builtin_amdgcn_mfma_f32_16x16x32_bf16(ah, bl[ni], acc[mi][ni], 0, 0, 0);
        acc[mi][ni] = __builtin_amdgcn_mfma_f32_16x16x32_bf16(al, bh[ni], acc[mi][ni], 0, 0, 0);
      }
    }
    __builtin_amdgcn_s_setprio(0);
  }

  const int col_l = l & 15;
  const int row_l = (l >> 4) * 4;
#pragma unroll
  for (int mi = 0; mi < 4; mi++) {
#pragma unroll
    for (int ni = 0; ni < 6; ni++) {
      int col = n0 + wn + ni * 16 + col_l;
      float bv = bias[col];
#pragma unroll
      for (int r = 0; r < 4; r++) {
        int row = m0 + wm + mi * 16 + row_l + r;
        float v = acc[mi][ni][r] + bv;
        if (RES) v += Rres[(size_t)row * N + col];
        if (ACT == 2) v = tanhf(v);
        Cf[(size_t)row * N + col] = v;
      }
    }
  }
}

// ---------------- MFMA split-bf16 attention (unchanged) ----------
__global__ __launch_bounds__(256, 2) void attn_kernel(
    const float* __restrict__ qkv, short* __restrict__ t1h,
    short* __restrict__ t1l) {
  __shared__ short lds[16384];
  const int qt = blockIdx.x, h = blockIdx.y, b = blockIdx.z;
  const int t = threadIdx.x;
  const int w = t >> 6, l = t & 63;
  const int li = l & 15, lh = l >> 4;

  short* kh = lds;
  short* kl = lds + 4096;
  short* ph = lds + 8192 + w * 2048;
  short* pl = ph + 1024;

  const int tok0 = b * S_ + qt * 64;

  bf16x8 qh[2], ql[2];
  {
    const float* qrow = qkv + (size_t)(tok0 + w * 16 + li) * 2304 + h * 64 + lh * 8;
#pragma unroll
    for (int s = 0; s < 2; s++) {
      float4 f0 = *(const float4*)(qrow + s * 32);
      float4 f1 = *(const float4*)(qrow + s * 32 + 4);
      float f[8] = {f0.x, f0.y, f0.z, f0.w, f1.x, f1.y, f1.z, f1.w};
      bf16x8 hv, lv;
#pragma unroll
      for (int j = 0; j < 8; j++) {
        short hs, ls2;
        split_bf16(f[j], hs, ls2);
        hv[j] = hs; lv[j] = ls2;
      }
      qh[s] = hv; ql[s] = lv;
    }
  }

  const int skk = t >> 2, sd0 = (t & 3) * 16;

  f32x4 acc[16] = {};

  const float* kbase = qkv + (size_t)(b * S_) * 2304 + 768 + h * 64;
#pragma unroll
  for (int c = 0; c < 4; c++) {
    __syncthreads();
    {
      const float* src = kbase + (size_t)(c * 64 + skk) * 2304 + sd0;
#pragma unroll
      for (int i = 0; i < 4; i++) {
        float4 f = *(const float4*)(src + i * 4);
        int d = sd0 + i * 4;
        short4 hv, lv;
        split_bf16(f.x, hv.x, lv.x);
        split_bf16(f.y, hv.y, lv.y);
        split_bf16(f.z, hv.z, lv.z);
        split_bf16(f.w, hv.w, lv.w);
        int off = skk * 64 + ((((d >> 3) ^ (skk & 7)) & 7) << 3) + (d & 7);
        *(short4*)(kh + off) = hv;
        *(short4*)(kl + off) = lv;
      }
    }
    __syncthreads();
#pragma unroll
    for (int nn = 0; nn < 4; nn++) {
      const int krow = nn * 16 + li;
#pragma unroll
      for (int s = 0; s < 2; s++) {
        const int off = krow * 64 + ((((s * 4 + lh) ^ (li & 7)) & 7) << 3);
        bf16x8 bh = *(const bf16x8*)(kh + off);
        bf16x8 bl = *(const bf16x8*)(kl + off);
        acc[c * 4 + nn] = __builtin_amdgcn_mfma_f32_16x16x32_bf16(qh[s], bh, acc[c * 4 + nn], 0, 0, 0);
        acc[c * 4 + nn] = __builtin_amdgcn_mfma_f32_16x16x32_bf16(qh[s], bl, acc[c * 4 + nn], 0, 0, 0);
        acc[c * 4 + nn] = __builtin_amdgcn_mfma_f32_16x16x32_bf16(ql[s], bh, acc[c * 4 + nn], 0, 0, 0);
      }
    }
  }

  float rs_[4];
#pragma unroll
  for (int r = 0; r < 4; r++) {
    float m = -3.4e38f;
#pragma unroll
    for (int fi = 0; fi < 16; fi++) m = fmaxf(m, acc[fi][r]);
#pragma unroll
    for (int off = 8; off; off >>= 1) m = fmaxf(m, __shfl_xor(m, off));
    float sum = 0.f;
#pragma unroll
    for (int fi = 0; fi < 16; fi++) {
      float p = expf((acc[fi][r] - m) * 0.125f);
      acc[fi][r] = p;
      sum += p;
    }
#pragma unroll
    for (int off = 8; off; off >>= 1) sum += __shfl_xor(sum, off);
    rs_[r] = sum;
  }

  f32x4 oacc[4] = {};
  const float* vbase = qkv + (size_t)(b * S_) * 2304 + 1536 + h * 64;
#pragma unroll
  for (int c = 0; c < 4; c++) {
    __syncthreads();
    {
      const float* src = vbase + (size_t)(c * 64 + skk) * 2304 + sd0;
#pragma unroll
      for (int i = 0; i < 4; i++) {
        float4 f = *(const float4*)(src + i * 4);
        float fv[4] = {f.x, f.y, f.z, f.w};
#pragma unroll
        for (int j = 0; j < 4; j++) {
          int d = sd0 + i * 4 + j;
          short hs, ls2;
          split_bf16(fv[j], hs, ls2);
          int sw = (d & 7) ^ ((d >> 3) & 7);
          int off = d * 64 + ((((skk >> 3) ^ sw) & 7) << 3) + (skk & 7);
          kh[off] = hs;
          kl[off] = ls2;
        }
      }
    }
#pragma unroll
    for (int nn = 0; nn < 4; nn++) {
#pragma unroll
      for (int r = 0; r < 4; r++) {
        const int q = lh * 4 + r;
        const int keyl = li + 16 * nn;
        short hs, ls2;
        split_bf16(acc[c * 4 + nn][r], hs, ls2);
        const int off = q * 64 + ((((keyl >> 3) ^ (q & 7)) & 7) << 3) + (keyl & 7);
        ph[off] = hs;
        pl[off] = ls2;
      }
    }
    __syncthreads();
    bf16x8 pah[2], pal[2];
#pragma unroll
    for (int s = 0; s < 2; s++) {
      const int off = li * 64 + ((((s * 4 + lh) ^ (li & 7)) & 7) << 3);
      pah[s] = *(const bf16x8*)(ph + off);
      pal[s] = *(const bf16x8*)(pl + off);
    }
#pragma unroll
    for (int dn = 0; dn < 4; dn++) {
      const int drow = dn * 16 + li;
      const int sw = ((drow & 7) ^ ((drow >> 3) & 7)) & 7;
#pragma unroll
      for (int s = 0; s < 2; s++) {
        const int off = drow * 64 + ((((s * 4 + lh) ^ sw) & 7) << 3);
        bf16x8 vh = *(const bf16x8*)(kh + off);
        bf16x8 vl = *(const bf16x8*)(kl + off);
        oacc[dn] = __builtin_amdgcn_mfma_f32_16x16x32_bf16(pah[s], vh, oacc[dn], 0, 0, 0);
        oacc[dn] = __builtin_amdgcn_mfma_f32_16x16x32_bf16(pah[s], vl, oacc[dn], 0, 0, 0);
        oacc[dn] = __builtin_amdgcn_mfma_f32_16x16x32_bf16(pal[s], vh, oacc[dn], 0, 0, 0);
      }
    }
  }

  float rinv[4];
#pragma unroll
  for (int r = 0; r < 4; r++) rinv[r] = 1.f / rs_[r];
#pragma unroll
  for (int dn = 0; dn < 4; dn++) {
#pragma unroll
    for (int r = 0; r < 4; r++) {
      float v = oacc[dn][r] * rinv[r];
      short hs, ls2;
      split_bf16(v, hs, ls2);
      size_t oidx = (size_t)(tok0 + w * 16 + lh * 4 + r) * E_ + h * 64 + dn * 16 + li;
      t1h[oidx] = hs;
      t1l[oidx] = ls2;
    }
  }
}

// ---------------- cosine similarity ----------------
__global__ __launch_bounds__(256) void cos_kernel(
    const float* __restrict__ a, const float* __restrict__ o,
    float* __restrict__ cosv) {
  int row = blockIdx.x;
  int t = threadIdx.x;
  const float* ar = a + (size_t)row * E_;
  const float* orr = o + (size_t)row * E_;
  float d = 0.f, na = 0.f, nb = 0.f;
#pragma unroll
  for (int j = 0; j < 3; j++) {
    float av = ar[t + 256 * j], ov = orr[t + 256 * j];
    d = fmaf(av, ov, d);
    na = fmaf(av, av, na);
    nb = fmaf(ov, ov, nb);
  }
  d = block_sum256(d);
  na = block_sum256(na);
  nb = block_sum256(nb);
  if (t == 0) cosv[row] = d / fmaxf(sqrtf(na) * sqrtf(nb), 1e-8f);
}

// ---------------- final selection: rank-based parallel top-k ----------------
__global__ __launch_bounds__(256) void select_kernel(
    const float* __restrict__ cosv, const int* __restrict__ typ,
    const float* __restrict__ gh, const float* __restrict__ gt,
    float* __restrict__ out) {
  __shared__ float vals[256];
  int b = blockIdx.x, t = threadIdx.x;
  int idx = b * 256 + t;
  int ty = typ[idx];
  float c = cosv[idx];
  float res = 0.f;

  float eh = (ty == 1) ? expf(c) : 0.f;
  float sh = block_sum256(eh);
  float glh = (ty == 1) ? (logf(eh / sh) + gh[idx]) : NEGV;
  vals[t] = glh;
  __syncthreads();
  {
    int rank = 0;
#pragma unroll
    for (int j = 0; j < 64; ++j) {
      float4 q = *(const float4*)&vals[j * 4];
      rank += (q.x > glh) || (q.x == glh && (j * 4 + 0) < t);
      rank += (q.y > glh) || (q.y == glh && (j * 4 + 1) < t);
      rank += (q.z > glh) || (q.z == glh && (j * 4 + 2) < t);
      rank += (q.w > glh) || (q.w == glh && (j * 4 + 3) < t);
    }
    if (ty == 1 && rank < 64) res += 1.f;
  }
  __syncthreads();

  float et = (ty == 2) ? expf(c) : 0.f;
  float st = block_sum256(et);
  float glt = (ty == 2) ? (logf(1.f - et / st) + gt[idx]) : NEGV;
  vals[t] = glt;
  __syncthreads();
  {
    int rank = 0;
#pragma unroll
    for (int j = 0; j < 64; ++j) {
      float4 q = *(const float4*)&vals[j * 4];
      rank += (q.x > glt) || (q.x == glt && (j * 4 + 0) < t);
      rank += (q.y > glt) || (q.y == glt && (j * 4 + 1) < t);
      rank += (q.z > glt) || (q.z == glt && (j * 4 + 2) < t);
      rank += (q.w > glt) || (q.w == glt && (j * 4 + 3) < t);
    }
    if (ty == 2 && rank < 63) res += 1.f;
  }
  out[idx] = res;
}

// ---------------- host side ----------------
static void launch_gemm(int act, int res, int osplit, const short* Ahi,
                        const short* Alo, const short* Whi, const short* Wlo,
                        const float* bias, const float* R, float* Cf,
                        short* Chi, short* Clo, int M, int N, int K,
                        hipStream_t s) {
  int nx = N / 128, ny = M / 128;
  int nwg = nx * ny;
  int cpx = nwg / 8;
  dim3 grid(nwg), blk(256);
  if (osplit) {
    gemm_dp<1, 0, 1><<<grid, blk, 0, s>>>(Ahi, Alo, Whi, Wlo, bias, R, Cf, Chi, Clo, M, N, K, nx, cpx);
  } else if (act == 2) {
    gemm_dp<2, 0, 0><<<grid, blk, 0, s>>>(Ahi, Alo, Whi, Wlo, bias, R, Cf, Chi, Clo, M, N, K, nx, cpx);
  } else if (res) {
    gemm_dp<0, 1, 0><<<grid, blk, 0, s>>>(Ahi, Alo, Whi, Wlo, bias, R, Cf, Chi, Clo, M, N, K, nx, cpx);
  } else {
    gemm_dp<0, 0, 0><<<grid, blk, 0, s>>>(Ahi, Alo, Whi, Wlo, bias, R, Cf, Chi, Clo, M, N, K, nx, cpx);
  }
}

static void launch_gemm2(int act, int res, const short* Ahi, const short* Alo,
                         const short* Whi, const short* Wlo, const float* bias,
                         const float* R, float* Cf, int M, int N, int K,
                         hipStream_t s) {
  int nx = N / 192, ny = M / 128;
  int nwg = nx * ny;  // 768 (qkv) / 256 (out, lin2, dense): % 8 == 0
  int cpx = nwg / 8;
  dim3 grid(nwg), blk(256);
  if (act == 2) {
    gemm_dp2<2, 0><<<grid, blk, 0, s>>>(Ahi, Alo, Whi, Wlo, bias, R, Cf, M, N, K, nx, cpx);
  } else if (res) {
    gemm_dp2<0, 1><<<grid, blk, 0, s>>>(Ahi, Alo, Whi, Wlo, bias, R, Cf, M, N, K, nx, cpx);
  } else {
    gemm_dp2<0, 0><<<grid, blk, 0, s>>>(Ahi, Alo, Whi, Wlo, bias, R, Cf, M, N, K, nx, cpx);
  }
}

extern "C" void kernel_launch(void* const* d_in, const int* in_sizes, int n_in,
                              void* d_out, int out_size, void* d_ws,
                              size_t ws_size, hipStream_t stream) {
  const float* tok = (const float*)d_in[0];
  const int* pos = (const int*)d_in[2];
  const int* typ = (const int*)d_in[3];
  const float* gh = (const float*)d_in[4];
  const float* gt = (const float*)d_in[5];
  const float* pe = (const float*)d_in[6];
  const float* temb = (const float*)d_in[7];
  const float* ln_w = (const float*)d_in[8];
  const float* ln_b = (const float*)d_in[9];
  const float* dense_w = (const float*)d_in[10];
  const float* dense_b = (const float*)d_in[11];
  const float* qkv_w = (const float*)d_in[12];
  const float* qkv_b = (const float*)d_in[13];
  const float* out_w = (const float*)d_in[14];
  const float* out_b = (const float*)d_in[15];
  const float* ln1_w = (const float*)d_in[16];
  const float* ln1_b = (const float*)d_in[17];
  const float* lin1_w = (const float*)d_in[18];
  const float* lin1_b = (const float*)d_in[19];
  const float* lin2_w = (const float*)d_in[20];
  const float* lin2_b = (const float*)d_in[21];
  const float* ln2_w = (const float*)d_in[22];
  const float* ln2_b = (const float*)d_in[23];

  const int M = B_ * S_;
  const size_t NX = (size_t)M * E_;
  const size_t NQKV = (size_t)M * 3 * E_;
  const size_t NFF = (size_t)M * FF_;

  const size_t oQ = 0;
  const size_t oO = oQ + 2 * (size_t)3 * E_ * E_;
  const size_t oL1 = oO + 2 * (size_t)E_ * E_;
  const size_t oL2 = oL1 + 2 * (size_t)FF_ * E_;
  const size_t oD = oL2 + 2 * (size_t)E_ * FF_;
  const size_t WTOT = oD + (size_t)E_ * E_;

  float* ws = (float*)d_ws;
  float* x = ws;
  float* t2 = x + NX;
  float* shared = t2 + NX;
  short* x_hi = (short*)(shared + NQKV);
  short* x_lo = x_hi + NX;
  short* t1_hi = x_lo + NX;
  short* t1_lo = t1_hi + NX;
  short* w_hi = t1_lo + NX;
  short* w_lo = w_hi + WTOT;
  float* cosb = (float*)(w_lo + WTOT);

  short* big_hi = (short*)shared;
  short* big_lo = big_hi + NFF;

  // ---- split weights into bf16 hi/lo planes ----
  {
    int n4;
    n4 = (int)(2 * 3 * E_ * E_ / 4);
    split_kernel<<<(n4 + 255) / 256, 256, 0, stream>>>(qkv_w, w_hi + oQ, w_lo + oQ, n4);
    n4 = (int)(2 * E_ * E_ / 4);
    split_kernel<<<(n4 + 255) / 256, 256, 0, stream>>>(out_w, w_hi + oO, w_lo + oO, n4);
    n4 = (int)(2 * FF_ * E_ / 4);
    split_kernel<<<(n4 + 255) / 256, 256, 0, stream>>>(lin1_w, w_hi + oL1, w_lo + oL1, n4);
    n4 = (int)(2 * E_ * FF_ / 4);
    split_kernel<<<(n4 + 255) / 256, 256, 0, stream>>>(lin2_w, w_hi + oL2, w_lo + oL2, n4);
    n4 = (int)(E_ * E_ / 4);
    split_kernel<<<(n4 + 255) / 256, 256, 0, stream>>>(dense_w, w_hi + oD, w_lo + oD, n4);
  }

  // ---- embed + LN ----
  embed_ln_kernel<<<M, 256, 0, stream>>>(tok, pos, typ, pe, temb, ln_w, ln_b,
                                         x, x_hi, x_lo);

  for (int l = 0; l < L_; l++) {
    const size_t wq = oQ + (size_t)l * 3 * E_ * E_;
    const size_t wo = oO + (size_t)l * E_ * E_;
    const size_t w1 = oL1 + (size_t)l * FF_ * E_;
    const size_t w2 = oL2 + (size_t)l * E_ * FF_;
    // qkv = x @ qkv_w^T + b  -> f32 (shared)   N=2304 % 192 == 0
    launch_gemm2(0, 0, x_hi, x_lo, w_hi + wq, w_lo + wq,
                 qkv_b + (size_t)l * 3 * E_, nullptr, shared, M, 3 * E_, E_,
                 stream);
    // attention -> t1 splits (MFMA)
    attn_kernel<<<dim3(4, H_, B_), 256, 0, stream>>>(shared, t1_hi, t1_lo);
    // t2 = x + t1 @ out_w^T + b                N=768 % 192 == 0
    launch_gemm2(0, 1, t1_hi, t1_lo, w_hi + wo, w_lo + wo,
                 out_b + (size_t)l * E_, x, t2, M, E_, E_, stream);
    // x = LN(t2)
    ln_kernel<<<M, 256, 0, stream>>>(t2, ln1_w + (size_t)l * E_,
                                     ln1_b + (size_t)l * E_, x, x_hi, x_lo);
    // big = relu(x @ lin1_w^T + b) -> splits   N=2048: keep 128^2 kernel
    launch_gemm(1, 0, 1, x_hi, x_lo, w_hi + w1, w_lo + w1,
                lin1_b + (size_t)l * FF_, nullptr, nullptr, big_hi, big_lo,
                M, FF_, E_, stream);
    // t2 = x + big @ lin2_w^T + b              N=768 % 192 == 0
    launch_gemm2(0, 1, big_hi, big_lo, w_hi + w2, w_lo + w2,
                 lin2_b + (size_t)l * E_, x, t2, M, E_, FF_, stream);
    // x = LN(t2)
    ln_kernel<<<M, 256, 0, stream>>>(t2, ln2_w + (size_t)l * E_,
                                     ln2_b + (size_t)l * E_, x, x_hi, x_lo);
  }

  // final LN -> splits only (f32 output dead; skip the write)
  ln_kernel<<<M, 256, 0, stream>>>(x, ln_w, ln_b, nullptr, t1_hi, t1_lo);
  // dense: tanh(t1 @ dense_w^T + b) -> f32     N=768 % 192 == 0
  launch_gemm2(2, 0, t1_hi, t1_lo, w_hi + oD, w_lo + oD, dense_b, nullptr,
               shared, M, E_, E_, stream);
  // cos
  cos_kernel<<<M, 256, 0, stream>>>(tok, shared, cosb);
  // selection
  select_kernel<<<B_, 256, 0, stream>>>(cosb, typ, gh, gt, (float*)d_out);
}